// Round 9
// baseline (315.313 us; speedup 1.0000x reference)
//
#include <hip/hip_runtime.h>
#include <math.h>

#define B_    8
#define C_    128
#define D_    128
#define L_    4096
#define NPOS_ 32768
#define NC_   256          // scan chunks per batch
#define S_    16           // chunk length
#define MFL_  1048576

typedef __attribute__((ext_vector_type(8))) short short8;
typedef __attribute__((ext_vector_type(4))) float f32x4;

__device__ __forceinline__ float siluf(float x) { return x / (1.f + __expf(-x)); }
__device__ __forceinline__ float softplusf(float x) {
    if (x > 20.f) return x;
    return __logf(1.f + __expf(x));
}
__device__ __forceinline__ unsigned short f2bf(float f) {
    unsigned int u = __float_as_uint(f);
    u = (u + 0x7FFFu + ((u >> 16) & 1u)) >> 16;
    return (unsigned short)u;
}
__device__ __forceinline__ float bf2f(unsigned short h) {
    return __uint_as_float(((unsigned int)h) << 16);
}
// a[n] = exp(dl*Ar[n]); fast path uses Ar[n] ~= -(n+1) (validated by caller)
__device__ __forceinline__ void scan_as(float dl, const float* Ar, bool fast, float* a) {
    if (fast) {
        float e1 = __expf(-dl);
        a[0] = e1;
        a[1] = e1 * e1;
        a[2] = a[1] * e1;
        a[3] = a[1] * a[1];
        a[4] = a[3] * e1;
        a[5] = a[3] * a[1];
        a[6] = a[5] * e1;
        a[7] = a[3] * a[3];
    } else {
        #pragma unroll
        for (int n = 0; n < 8; ++n) a[n] = __expf(dl * Ar[n]);
    }
}

// ---- K1: weight cvt (folded k0) + grouped 1x1 (w1)->t1 bf16 ; silu(g1x1(w2))->x2s bf16 ----
__global__ __launch_bounds__(256) void k1_g1x1(const float* __restrict__ x,
                                               const float* __restrict__ w1,
                                               const float* __restrict__ w2,
                                               const float* __restrict__ inW,
                                               const float* __restrict__ OW,
                                               const float* __restrict__ xpw,
                                               unsigned short* __restrict__ inWb,
                                               unsigned short* __restrict__ OWb,
                                               unsigned short* __restrict__ xpwb,
                                               unsigned short* __restrict__ t1b,
                                               unsigned short* __restrict__ x2sb) {
    __shared__ float xs[16 * 128];
    int t = threadIdx.x;
    // folded k0: 512 blocks x 102 = 52224 conversions
    {
        int i = blockIdx.x * 102 + t;
        if (t < 102 && i < 52224) {
            if (i < 32768)      inWb[i] = f2bf(inW[i]);
            else if (i < 49152) OWb[i - 32768] = f2bf(OW[i - 32768]);
            else                xpwb[i - 49152] = f2bf(xpw[i - 49152]);
        }
    }
    int d = t & 127, ph = t >> 7;
    int g = d >> 5, o = d & 31;
    float w1r[32], w2r[32];
    #pragma unroll
    for (int i = 0; i < 32; ++i) {
        w1r[i] = w1[g * 1024 + o * 32 + i];
        w2r[i] = w2[g * 1024 + o * 32 + i];
    }
    int pos0 = blockIdx.x * 64;
    for (int it = 0; it < 4; ++it) {
        int p0 = pos0 + it * 16;
        #pragma unroll
        for (int q = 0; q < 2; ++q) {
            int fi = t * 2 + q;
            *(float4*)&xs[fi * 4] = *(const float4*)&x[p0 * 128 + fi * 4];
        }
        __syncthreads();
        #pragma unroll
        for (int q = 0; q < 8; ++q) {
            int pl = ph * 8 + q;
            float a1 = 0.f, a2 = 0.f;
            const float* xr = &xs[pl * 128 + g * 32];
            #pragma unroll
            for (int i4 = 0; i4 < 8; ++i4) {
                float4 xv = *(const float4*)&xr[i4 * 4];
                a1 += xv.x * w1r[i4*4] + xv.y * w1r[i4*4+1] + xv.z * w1r[i4*4+2] + xv.w * w1r[i4*4+3];
                a2 += xv.x * w2r[i4*4] + xv.y * w2r[i4*4+1] + xv.z * w2r[i4*4+2] + xv.w * w2r[i4*4+3];
            }
            int pos = p0 + pl;
            t1b[pos * 128 + d]  = f2bf(a1);
            x2sb[pos * 128 + d] = f2bf(siluf(a2));
        }
        __syncthreads();
    }
}

// ---- K2: depthwise 3x3 SAME + silu. bf16 in/out ----
__global__ __launch_bounds__(128) void k2_dwconv(const unsigned short* __restrict__ t1b,
                                                 const float* __restrict__ dw,
                                                 unsigned short* __restrict__ x1cb) {
    int d = threadIdx.x;
    float dwr[9];
    #pragma unroll
    for (int k = 0; k < 9; ++k) dwr[k] = dw[k * 128 + d];
    int bid = blockIdx.x;
    int wt = bid & 7, ht = (bid >> 3) & 7, b = bid >> 6;
    int h0 = ht * 8, w0 = wt * 8;
    float rows[10][10];
    #pragma unroll
    for (int r = 0; r < 10; ++r) {
        int hh = h0 - 1 + r;
        bool hv = (hh >= 0) && (hh < 64);
        #pragma unroll
        for (int c = 0; c < 10; ++c) {
            int w = w0 - 1 + c;
            bool wvv = (w >= 0) && (w < 64);
            rows[r][c] = (hv && wvv) ? bf2f(t1b[((b * 64 + hh) * 64 + w) * 128 + d]) : 0.f;
        }
    }
    #pragma unroll
    for (int hi = 0; hi < 8; ++hi) {
        #pragma unroll
        for (int wi = 0; wi < 8; ++wi) {
            float acc = rows[hi][wi]     * dwr[0] + rows[hi][wi+1]   * dwr[1] + rows[hi][wi+2]   * dwr[2]
                      + rows[hi+1][wi]   * dwr[3] + rows[hi+1][wi+1] * dwr[4] + rows[hi+1][wi+2] * dwr[5]
                      + rows[hi+2][wi]   * dwr[6] + rows[hi+2][wi+1] * dwr[7] + rows[hi+2][wi+2] * dwr[8];
            x1cb[((b * 64 + h0 + hi) * 64 + w0 + wi) * 128 + d] = f2bf(siluf(acc));
        }
    }
}

// ---- K3: in_proj via bf16 MFMA -> urawb bf16, zb bf16 ----
__global__ __launch_bounds__(256) void k3_mfma(const unsigned short* __restrict__ Abf,
                                               const unsigned short* __restrict__ Bbf,
                                               unsigned short* __restrict__ urawb,
                                               unsigned short* __restrict__ zb) {
    __shared__ unsigned short Al[128 * 72];
    __shared__ unsigned short Bl[128 * 72];
    int t = threadIdx.x;
    int mtile = blockIdx.x >> 1, ntile = blockIdx.x & 1;
    int pos0 = mtile * 128, n0g = ntile * 128;
    int lane = t & 63, wv = t >> 6;
    int m0 = (wv & 1) * 64, n0w = (wv >> 1) * 64;
    int lanem = lane & 15, laneq = lane >> 4;
    f32x4 acc[4][4];
    #pragma unroll
    for (int i = 0; i < 4; ++i)
        #pragma unroll
        for (int j = 0; j < 4; ++j) acc[i][j] = (f32x4){0.f, 0.f, 0.f, 0.f};
    for (int kc = 0; kc < 2; ++kc) {
        #pragma unroll
        for (int q = 0; q < 4; ++q) {
            int c = t + q * 256;
            int row = c >> 3, col = c & 7;
            *(int4*)&Al[row * 72 + col * 8] = *(const int4*)&Abf[(pos0 + row) * 128 + kc * 64 + col * 8];
            *(int4*)&Bl[row * 72 + col * 8] = *(const int4*)&Bbf[(n0g + row) * 128 + kc * 64 + col * 8];
        }
        __syncthreads();
        #pragma unroll
        for (int ks = 0; ks < 2; ++ks) {
            short8 af[4], bfr[4];
            #pragma unroll
            for (int mi = 0; mi < 4; ++mi)
                af[mi] = *(const short8*)&Al[(m0 + mi * 16 + lanem) * 72 + ks * 32 + laneq * 8];
            #pragma unroll
            for (int ni = 0; ni < 4; ++ni)
                bfr[ni] = *(const short8*)&Bl[(n0w + ni * 16 + lanem) * 72 + ks * 32 + laneq * 8];
            #pragma unroll
            for (int mi = 0; mi < 4; ++mi)
                #pragma unroll
                for (int ni = 0; ni < 4; ++ni)
                    acc[mi][ni] = __builtin_amdgcn_mfma_f32_16x16x32_bf16(af[mi], bfr[ni], acc[mi][ni], 0, 0, 0);
        }
        __syncthreads();
    }
    unsigned short* dst = ntile ? zb : urawb;
    #pragma unroll
    for (int mi = 0; mi < 4; ++mi)
        #pragma unroll
        for (int ni = 0; ni < 4; ++ni)
            #pragma unroll
            for (int r = 0; r < 4; ++r) {
                int m = pos0 + m0 + mi * 16 + laneq * 4 + r;
                int n = n0w + ni * 16 + lanem;
                dst[m * 128 + n] = f2bf(acc[mi][ni][r]);
            }
}

// ---- K4: conv1d+silu -> usb bf16 ; x_proj MFMA ; delta fp32 ; Bm/Cm ----
__global__ __launch_bounds__(256) void k4_convproj(const unsigned short* __restrict__ urawb,
                                                   const float* __restrict__ cw,
                                                   const float* __restrict__ cb,
                                                   const unsigned short* __restrict__ xpwb,
                                                   const float* __restrict__ dtw,
                                                   const float* __restrict__ dtb,
                                                   unsigned short* __restrict__ usb,
                                                   float* __restrict__ delta,
                                                   float* __restrict__ Bm,
                                                   float* __restrict__ Cm) {
    __shared__ unsigned short uA[64 * 136];
    __shared__ unsigned short xB[32 * 136];
    __shared__ float xdb[64 * 36];
    int t = threadIdx.x;
    int d = t & 127, ph = t >> 7;
    for (int i = t; i < 32 * 128; i += 256) {
        int n = i >> 7, k = i & 127;
        xB[n * 136 + k] = (n < 24) ? xpwb[n * 128 + k] : (unsigned short)0;
    }
    float cw0 = cw[d * 3 + 0], cw1 = cw[d * 3 + 1], cw2 = cw[d * 3 + 2], cbr = cb[d];
    float dtwr[8];
    #pragma unroll
    for (int r = 0; r < 8; ++r) dtwr[r] = dtw[d * 8 + r];
    float dtbr = dtb[d];

    int gpos0 = blockIdx.x * 64;
    int ll0 = (gpos0 & 4095) + ph * 32;
    int base = (gpos0 + ph * 32) * 128 + d;
    float ur0 = (ll0 >= 2) ? bf2f(urawb[base - 256]) : 0.f;
    float ur1 = (ll0 >= 1) ? bf2f(urawb[base - 128]) : 0.f;
    #pragma unroll
    for (int q = 0; q < 32; ++q) {
        float urq = bf2f(urawb[base + q * 128]);
        float v = siluf(ur0 * cw0 + ur1 * cw1 + urq * cw2 + cbr);
        unsigned short vb = f2bf(v);
        usb[base + q * 128] = vb;
        uA[(ph * 32 + q) * 136 + d] = vb;
        ur0 = ur1; ur1 = urq;
    }
    __syncthreads();
    int lane = t & 63, wv = t >> 6;
    int lanem = lane & 15, laneq = lane >> 4;
    f32x4 accx[2];
    accx[0] = (f32x4){0.f, 0.f, 0.f, 0.f};
    accx[1] = (f32x4){0.f, 0.f, 0.f, 0.f};
    #pragma unroll
    for (int ks = 0; ks < 4; ++ks) {
        short8 af = *(const short8*)&uA[(wv * 16 + lanem) * 136 + ks * 32 + laneq * 8];
        #pragma unroll
        for (int nj = 0; nj < 2; ++nj) {
            short8 bfr = *(const short8*)&xB[(nj * 16 + lanem) * 136 + ks * 32 + laneq * 8];
            accx[nj] = __builtin_amdgcn_mfma_f32_16x16x32_bf16(af, bfr, accx[nj], 0, 0, 0);
        }
    }
    #pragma unroll
    for (int nj = 0; nj < 2; ++nj)
        #pragma unroll
        for (int r = 0; r < 4; ++r)
            xdb[(wv * 16 + laneq * 4 + r) * 36 + nj * 16 + lanem] = accx[nj][r];
    __syncthreads();
    #pragma unroll
    for (int q = 0; q < 32; ++q) {
        int pl = ph * 32 + q;
        float dt = dtbr;
        #pragma unroll
        for (int r = 0; r < 8; ++r) dt += xdb[pl * 36 + r] * dtwr[r];
        delta[base + q * 128] = softplusf(dt);
    }
    for (int i = t; i < 1024; i += 256) {
        int p = i >> 4, j = i & 15;
        float v = xdb[p * 36 + 8 + j];
        int gp = gpos0 + p;
        if (j < 8) Bm[gp * 8 + j] = v;
        else       Cm[gp * 8 + (j - 8)] = v;
    }
}

// ---- K5: scan phase 1 (S=16, NC=256). grid B*NC=2048 x 128 thr ----
__global__ __launch_bounds__(128) void k5_scan1(const float* __restrict__ delta,
                                                const unsigned short* __restrict__ usb,
                                                const float* __restrict__ Bm,
                                                const float* __restrict__ A_log,
                                                float* __restrict__ cA,
                                                float* __restrict__ cB) {
    int d = threadIdx.x;
    int bc = blockIdx.x;
    int b = bc >> 8, c = bc & 255;
    float Ar[8]; bool fast = true;
    #pragma unroll
    for (int n = 0; n < 8; ++n) {
        Ar[n] = -__expf(A_log[d * 8 + n]);
        fast = fast && (fabsf(Ar[n] + (float)(n + 1)) < 2e-3f);
    }
    float h[8], ap[8];
    #pragma unroll
    for (int n = 0; n < 8; ++n) { h[n] = 0.f; ap[n] = 1.f; }
    int base  = (b * L_ + c * S_) * 128 + d;
    int bbase = (b * L_ + c * S_) * 8;
    #pragma unroll
    for (int s = 0; s < S_; ++s) {
        float dl = delta[base + s * 128];
        float uv = bf2f(usb[base + s * 128]);
        float du = dl * uv;
        float4 bm0 = *(const float4*)&Bm[bbase + s * 8];
        float4 bm1 = *(const float4*)&Bm[bbase + s * 8 + 4];
        float a[8];
        scan_as(dl, Ar, fast, a);
        ap[0] *= a[0]; h[0] = a[0] * h[0] + du * bm0.x;
        ap[1] *= a[1]; h[1] = a[1] * h[1] + du * bm0.y;
        ap[2] *= a[2]; h[2] = a[2] * h[2] + du * bm0.z;
        ap[3] *= a[3]; h[3] = a[3] * h[3] + du * bm0.w;
        ap[4] *= a[4]; h[4] = a[4] * h[4] + du * bm1.x;
        ap[5] *= a[5]; h[5] = a[5] * h[5] + du * bm1.y;
        ap[6] *= a[6]; h[6] = a[6] * h[6] + du * bm1.z;
        ap[7] *= a[7]; h[7] = a[7] * h[7] + du * bm1.w;
    }
    int obase = ((b * NC_ + c) * 128 + d) * 8;
    *(float4*)&cA[obase]     = make_float4(ap[0], ap[1], ap[2], ap[3]);
    *(float4*)&cA[obase + 4] = make_float4(ap[4], ap[5], ap[6], ap[7]);
    *(float4*)&cB[obase]     = make_float4(h[0], h[1], h[2], h[3]);
    *(float4*)&cB[obase + 4] = make_float4(h[4], h[5], h[6], h[7]);
}

// ---- K6: scan phase 2 (inter-chunk). 128 blocks x 64 thr -> 128 CUs active ----
__global__ __launch_bounds__(64) void k6_scan2(const float* __restrict__ cA,
                                               const float* __restrict__ cB,
                                               float* __restrict__ carry) {
    int gid = blockIdx.x * 64 + threadIdx.x;   // 0..8191
    int b = gid >> 10, dn = gid & 1023;
    float h = 0.f;
    #pragma unroll 4
    for (int c = 0; c < NC_; ++c) {
        int idx = (b * NC_ + c) * 1024 + dn;
        float a  = cA[idx];
        float bv = cB[idx];
        carry[idx] = h;
        h = a * h + bv;
    }
}

// ---- K7: scan phase 3 (S=16), emit y bf16. grid 2048 x 128 ----
__global__ __launch_bounds__(128) void k7_scan3(const float* __restrict__ delta,
                                                const unsigned short* __restrict__ usb,
                                                const float* __restrict__ Bm,
                                                const float* __restrict__ Cm,
                                                const unsigned short* __restrict__ zb,
                                                const float* __restrict__ A_log,
                                                const float* __restrict__ Dp,
                                                const float* __restrict__ carry,
                                                unsigned short* __restrict__ ybf) {
    int d = threadIdx.x;
    int bc = blockIdx.x;
    int b = bc >> 8, c = bc & 255;
    float Ar[8]; bool fast = true;
    #pragma unroll
    for (int n = 0; n < 8; ++n) {
        Ar[n] = -__expf(A_log[d * 8 + n]);
        fast = fast && (fabsf(Ar[n] + (float)(n + 1)) < 2e-3f);
    }
    float Dpr = Dp[d];
    int cbase = ((b * NC_ + c) * 128 + d) * 8;
    float4 h0 = *(const float4*)&carry[cbase];
    float4 h1 = *(const float4*)&carry[cbase + 4];
    float h[8] = {h0.x, h0.y, h0.z, h0.w, h1.x, h1.y, h1.z, h1.w};
    int base  = (b * L_ + c * S_) * 128 + d;
    int bbase = (b * L_ + c * S_) * 8;
    #pragma unroll
    for (int s = 0; s < S_; ++s) {
        float dl = delta[base + s * 128];
        float uv = bf2f(usb[base + s * 128]);
        float zv = bf2f(zb[base + s * 128]);
        float du = dl * uv;
        float4 bm0 = *(const float4*)&Bm[bbase + s * 8];
        float4 bm1 = *(const float4*)&Bm[bbase + s * 8 + 4];
        float4 cm0 = *(const float4*)&Cm[bbase + s * 8];
        float4 cm1 = *(const float4*)&Cm[bbase + s * 8 + 4];
        float a[8];
        scan_as(dl, Ar, fast, a);
        h[0] = a[0] * h[0] + du * bm0.x;
        h[1] = a[1] * h[1] + du * bm0.y;
        h[2] = a[2] * h[2] + du * bm0.z;
        h[3] = a[3] * h[3] + du * bm0.w;
        h[4] = a[4] * h[4] + du * bm1.x;
        h[5] = a[5] * h[5] + du * bm1.y;
        h[6] = a[6] * h[6] + du * bm1.z;
        h[7] = a[7] * h[7] + du * bm1.w;
        float yv = h[0] * cm0.x + h[1] * cm0.y + h[2] * cm0.z + h[3] * cm0.w
                 + h[4] * cm1.x + h[5] * cm1.y + h[6] * cm1.z + h[7] * cm1.w;
        yv = (yv + uv * Dpr) * siluf(zv);
        ybf[base + s * 128] = f2bf(yv);
    }
}

// ---- K8a: out_proj via bf16 MFMA, 64-row tiles -> xzb bf16. grid 512 ----
__global__ __launch_bounds__(256) void k8a_mfma(const unsigned short* __restrict__ Abf,
                                                const unsigned short* __restrict__ Bbf,
                                                unsigned short* __restrict__ xzb) {
    __shared__ unsigned short Al[64 * 72];
    __shared__ unsigned short Bl[128 * 72];
    int t = threadIdx.x;
    int pos0 = blockIdx.x * 64;
    int lane = t & 63, wv = t >> 6;
    int lanem = lane & 15, laneq = lane >> 4;
    f32x4 acc[8];
    #pragma unroll
    for (int i = 0; i < 8; ++i) acc[i] = (f32x4){0.f, 0.f, 0.f, 0.f};
    for (int kc = 0; kc < 2; ++kc) {
        #pragma unroll
        for (int q = 0; q < 2; ++q) {
            int c = t + q * 256;
            int row = c >> 3, col = c & 7;
            *(int4*)&Al[row * 72 + col * 8] = *(const int4*)&Abf[(pos0 + row) * 128 + kc * 64 + col * 8];
        }
        #pragma unroll
        for (int q = 0; q < 4; ++q) {
            int c = t + q * 256;
            int row = c >> 3, col = c & 7;
            *(int4*)&Bl[row * 72 + col * 8] = *(const int4*)&Bbf[row * 128 + kc * 64 + col * 8];
        }
        __syncthreads();
        #pragma unroll
        for (int ks = 0; ks < 2; ++ks) {
            short8 af = *(const short8*)&Al[(wv * 16 + lanem) * 72 + ks * 32 + laneq * 8];
            #pragma unroll
            for (int ni = 0; ni < 8; ++ni) {
                short8 bfr = *(const short8*)&Bl[(ni * 16 + lanem) * 72 + ks * 32 + laneq * 8];
                acc[ni] = __builtin_amdgcn_mfma_f32_16x16x32_bf16(af, bfr, acc[ni], 0, 0, 0);
            }
        }
        __syncthreads();
    }
    #pragma unroll
    for (int ni = 0; ni < 8; ++ni)
        #pragma unroll
        for (int r = 0; r < 4; ++r) {
            int m = pos0 + wv * 16 + laneq * 4 + r;
            int n = ni * 16 + lanem;
            xzb[m * 128 + n] = f2bf(acc[ni][r]);
        }
}

// ---- K8b: LayerNorm + *x2s + grouped 1x1 (wout, fp32) -> out. 64 pos/block, grid 512 ----
__global__ __launch_bounds__(256) void k8b_epi(const unsigned short* __restrict__ xzb,
                                               const float* __restrict__ gamma,
                                               const float* __restrict__ beta,
                                               const unsigned short* __restrict__ x2sb,
                                               const float* __restrict__ wout,
                                               float* __restrict__ out) {
    __shared__ float woutL[4 * 1160];   // [g][o*36+i], g-skew 8 words -> conflict-free b128
    __shared__ float xfs[64 * 132];
    int t = threadIdx.x;
    int pos0 = blockIdx.x * 64;
    for (int idx = t; idx < 4096; idx += 256) {
        int g = idx >> 10, r = idx & 1023, o = r >> 5, i = r & 31;
        woutL[g * 1160 + o * 36 + i] = wout[idx];
    }
    int te = t & 31, tp = t >> 5;
    float gr[4], br[4];
    #pragma unroll
    for (int j = 0; j < 4; ++j) { gr[j] = gamma[te + 32 * j]; br[j] = beta[te + 32 * j]; }
    #pragma unroll
    for (int i = 0; i < 8; ++i) {
        int row = tp * 8 + i;
        int pos = pos0 + row;
        float v[4];
        #pragma unroll
        for (int j = 0; j < 4; ++j) v[j] = bf2f(xzb[pos * 128 + te + 32 * j]);
        float s  = v[0] + v[1] + v[2] + v[3];
        float s2 = v[0]*v[0] + v[1]*v[1] + v[2]*v[2] + v[3]*v[3];
        #pragma unroll
        for (int off = 16; off >= 1; off >>= 1) {
            s  += __shfl_xor(s, off, 64);
            s2 += __shfl_xor(s2, off, 64);
        }
        float m = s * (1.f / 128.f);
        float var = s2 * (1.f / 128.f) - m * m;
        float rstd = rsqrtf(var + 1e-5f);
        #pragma unroll
        for (int j = 0; j < 4; ++j) {
            float vv = (v[j] - m) * rstd * gr[j] + br[j];
            vv *= bf2f(x2sb[pos * 128 + te + 32 * j]);
            xfs[row * 132 + te + 32 * j] = vv;
        }
    }
    __syncthreads();
    // thread = (pos, g): xf row in registers, 32 outputs per thread
    int g = t & 3, pos = t >> 2;
    float xfr[32];
    #pragma unroll
    for (int i4 = 0; i4 < 8; ++i4)
        *(float4*)&xfr[i4 * 4] = *(const float4*)&xfs[pos * 132 + g * 32 + i4 * 4];
    const float* wg = &woutL[g * 1160];
    int obase = (pos0 + pos) * 128 + g * 32;
    #pragma unroll
    for (int ob = 0; ob < 8; ++ob) {
        float o4[4];
        #pragma unroll
        for (int oo = 0; oo < 4; ++oo) {
            int o = ob * 4 + oo;
            float acc = 0.f;
            #pragma unroll
            for (int i4 = 0; i4 < 8; ++i4) {
                float4 wv4 = *(const float4*)&wg[o * 36 + i4 * 4];
                acc += xfr[i4*4] * wv4.x + xfr[i4*4+1] * wv4.y
                     + xfr[i4*4+2] * wv4.z + xfr[i4*4+3] * wv4.w;
            }
            o4[oo] = acc;
        }
        *(float4*)&out[obase + ob * 4] = make_float4(o4[0], o4[1], o4[2], o4[3]);
    }
}

extern "C" void kernel_launch(void* const* d_in, const int* in_sizes, int n_in,
                              void* d_out, int out_size, void* d_ws, size_t ws_size,
                              hipStream_t stream) {
    (void)in_sizes; (void)n_in; (void)out_size; (void)ws_size;
    const float* x         = (const float*)d_in[0];
    const float* w1        = (const float*)d_in[1];
    const float* dw        = (const float*)d_in[2];
    const float* in_proj_w = (const float*)d_in[3];
    const float* conv1d_w  = (const float*)d_in[4];
    const float* conv1d_b  = (const float*)d_in[5];
    const float* x_proj_w  = (const float*)d_in[6];
    const float* dt_proj_w = (const float*)d_in[7];
    const float* dt_proj_b = (const float*)d_in[8];
    const float* A_log     = (const float*)d_in[9];
    const float* D_param   = (const float*)d_in[10];
    const float* out_proj_w= (const float*)d_in[11];
    const float* gamma     = (const float*)d_in[12];
    const float* beta      = (const float*)d_in[13];
    const float* w2        = (const float*)d_in[14];
    const float* wout      = (const float*)d_in[15];
    float* out = (float*)d_out;

    float* ws = (float*)d_ws;
    unsigned short* x2sb  = (unsigned short*)(ws);
    unsigned short* t1b   = (unsigned short*)(ws + 2  * (size_t)MFL_);
    unsigned short* x1cb  = (unsigned short*)(ws + 4  * (size_t)MFL_);
    unsigned short* urawb = (unsigned short*)(ws + 6  * (size_t)MFL_);
    unsigned short* zb    = (unsigned short*)(ws + 8  * (size_t)MFL_);
    unsigned short* ybf   = (unsigned short*)(ws + 10 * (size_t)MFL_);
    unsigned short* xzb   = (unsigned short*)(ws + 12 * (size_t)MFL_);
    unsigned short* usb   = (unsigned short*)(ws + 14 * (size_t)MFL_);
    float* delta = ws + 16 * (size_t)MFL_;            // 4M fl
    float* Bm    = ws + 20 * (size_t)MFL_;            // 262144
    float* Cm    = Bm + (size_t)NPOS_ * 8;            // 262144
    float* cA    = Cm + (size_t)NPOS_ * 8;            // 2M fl
    float* cB    = cA + 2 * (size_t)MFL_;             // 2M fl
    float* carry = cB + 2 * (size_t)MFL_;             // 2M fl
    unsigned short* inWb = (unsigned short*)(carry + 2 * (size_t)MFL_);
    unsigned short* OWb  = inWb + 32768;
    unsigned short* xpwb = OWb + 16384;

    k1_g1x1<<<512, 256, 0, stream>>>(x, w1, w2, in_proj_w, out_proj_w, x_proj_w,
                                     inWb, OWb, xpwb, t1b, x2sb);
    k2_dwconv<<<512, 128, 0, stream>>>(t1b, dw, x1cb);
    k3_mfma<<<512, 256, 0, stream>>>(x1cb, inWb, urawb, zb);
    k4_convproj<<<512, 256, 0, stream>>>(urawb, conv1d_w, conv1d_b, xpwb,
                                         dt_proj_w, dt_proj_b, usb, delta, Bm, Cm);
    k5_scan1<<<2048, 128, 0, stream>>>(delta, usb, Bm, A_log, cA, cB);
    k6_scan2<<<128, 64, 0, stream>>>(cA, cB, carry);
    k7_scan3<<<2048, 128, 0, stream>>>(delta, usb, Bm, Cm, zb, A_log, D_param, carry, ybf);
    k8a_mfma<<<512, 256, 0, stream>>>(ybf, OWb, xzb);
    k8b_epi<<<512, 256, 0, stream>>>(xzb, gamma, beta, x2sb, wout, out);
}

// Round 10
// 305.053 us; speedup vs baseline: 1.0336x; 1.0336x over previous
//
#include <hip/hip_runtime.h>
#include <math.h>

#define B_    8
#define C_    128
#define D_    128
#define L_    4096
#define NPOS_ 32768
#define NC_   256          // scan chunks per batch
#define S_    16           // chunk length
#define MFL_  1048576

typedef __attribute__((ext_vector_type(8))) short short8;
typedef __attribute__((ext_vector_type(4))) float f32x4;

__device__ __forceinline__ float siluf(float x) { return x / (1.f + __expf(-x)); }
__device__ __forceinline__ float softplusf(float x) {
    if (x > 20.f) return x;
    return __logf(1.f + __expf(x));
}
__device__ __forceinline__ unsigned short f2bf(float f) {
    unsigned int u = __float_as_uint(f);
    u = (u + 0x7FFFu + ((u >> 16) & 1u)) >> 16;
    return (unsigned short)u;
}
__device__ __forceinline__ float bf2f(unsigned short h) {
    return __uint_as_float(((unsigned int)h) << 16);
}
// a[n] = exp(dl*Ar[n]); fast path uses Ar[n] ~= -(n+1) (validated by caller)
__device__ __forceinline__ void scan_as(float dl, const float* Ar, bool fast, float* a) {
    if (fast) {
        float e1 = __expf(-dl);
        a[0] = e1;
        a[1] = e1 * e1;
        a[2] = a[1] * e1;
        a[3] = a[1] * a[1];
        a[4] = a[3] * e1;
        a[5] = a[3] * a[1];
        a[6] = a[5] * e1;
        a[7] = a[3] * a[3];
    } else {
        #pragma unroll
        for (int n = 0; n < 8; ++n) a[n] = __expf(dl * Ar[n]);
    }
}

// ---- K0: convert in_proj_w, out_proj_w, x_proj_w to bf16 ----
__global__ __launch_bounds__(256) void k0_cvt(const float* __restrict__ inW,
                                              const float* __restrict__ OW,
                                              const float* __restrict__ xpw,
                                              unsigned short* __restrict__ inWb,
                                              unsigned short* __restrict__ OWb,
                                              unsigned short* __restrict__ xpwb) {
    for (int i = blockIdx.x * 256 + threadIdx.x; i < 52224; i += gridDim.x * 256) {
        if (i < 32768)      inWb[i] = f2bf(inW[i]);
        else if (i < 49152) OWb[i - 32768] = f2bf(OW[i - 32768]);
        else                xpwb[i - 49152] = f2bf(xpw[i - 49152]);
    }
}

// ---- K1: grouped 1x1 (w1)->t1 bf16 ; silu(grouped 1x1 (w2))->x2s bf16 ----
__global__ __launch_bounds__(256) void k1_g1x1(const float* __restrict__ x,
                                               const float* __restrict__ w1,
                                               const float* __restrict__ w2,
                                               unsigned short* __restrict__ t1b,
                                               unsigned short* __restrict__ x2sb) {
    __shared__ float xs[16 * 128];
    int t = threadIdx.x;
    int d = t & 127, ph = t >> 7;
    int g = d >> 5, o = d & 31;
    float w1r[32], w2r[32];
    #pragma unroll
    for (int i = 0; i < 32; ++i) {
        w1r[i] = w1[g * 1024 + o * 32 + i];
        w2r[i] = w2[g * 1024 + o * 32 + i];
    }
    int pos0 = blockIdx.x * 64;
    for (int it = 0; it < 4; ++it) {
        int p0 = pos0 + it * 16;
        #pragma unroll
        for (int q = 0; q < 2; ++q) {
            int fi = t * 2 + q;
            *(float4*)&xs[fi * 4] = *(const float4*)&x[p0 * 128 + fi * 4];
        }
        __syncthreads();
        #pragma unroll
        for (int q = 0; q < 8; ++q) {
            int pl = ph * 8 + q;
            float a1 = 0.f, a2 = 0.f;
            const float* xr = &xs[pl * 128 + g * 32];
            #pragma unroll
            for (int i4 = 0; i4 < 8; ++i4) {
                float4 xv = *(const float4*)&xr[i4 * 4];
                a1 += xv.x * w1r[i4*4] + xv.y * w1r[i4*4+1] + xv.z * w1r[i4*4+2] + xv.w * w1r[i4*4+3];
                a2 += xv.x * w2r[i4*4] + xv.y * w2r[i4*4+1] + xv.z * w2r[i4*4+2] + xv.w * w2r[i4*4+3];
            }
            int pos = p0 + pl;
            t1b[pos * 128 + d]  = f2bf(a1);
            x2sb[pos * 128 + d] = f2bf(siluf(a2));
        }
        __syncthreads();
    }
}

// ---- K2: depthwise 3x3 SAME + silu. bf16 in/out ----
__global__ __launch_bounds__(128) void k2_dwconv(const unsigned short* __restrict__ t1b,
                                                 const float* __restrict__ dw,
                                                 unsigned short* __restrict__ x1cb) {
    int d = threadIdx.x;
    float dwr[9];
    #pragma unroll
    for (int k = 0; k < 9; ++k) dwr[k] = dw[k * 128 + d];
    int bid = blockIdx.x;
    int wt = bid & 7, ht = (bid >> 3) & 7, b = bid >> 6;
    int h0 = ht * 8, w0 = wt * 8;
    float rows[10][10];
    #pragma unroll
    for (int r = 0; r < 10; ++r) {
        int hh = h0 - 1 + r;
        bool hv = (hh >= 0) && (hh < 64);
        #pragma unroll
        for (int c = 0; c < 10; ++c) {
            int w = w0 - 1 + c;
            bool wvv = (w >= 0) && (w < 64);
            rows[r][c] = (hv && wvv) ? bf2f(t1b[((b * 64 + hh) * 64 + w) * 128 + d]) : 0.f;
        }
    }
    #pragma unroll
    for (int hi = 0; hi < 8; ++hi) {
        #pragma unroll
        for (int wi = 0; wi < 8; ++wi) {
            float acc = rows[hi][wi]     * dwr[0] + rows[hi][wi+1]   * dwr[1] + rows[hi][wi+2]   * dwr[2]
                      + rows[hi+1][wi]   * dwr[3] + rows[hi+1][wi+1] * dwr[4] + rows[hi+1][wi+2] * dwr[5]
                      + rows[hi+2][wi]   * dwr[6] + rows[hi+2][wi+1] * dwr[7] + rows[hi+2][wi+2] * dwr[8];
            x1cb[((b * 64 + h0 + hi) * 64 + w0 + wi) * 128 + d] = f2bf(siluf(acc));
        }
    }
}

// ---- K3: in_proj via bf16 MFMA -> urawb bf16, zb bf16 ----
__global__ __launch_bounds__(256) void k3_mfma(const unsigned short* __restrict__ Abf,
                                               const unsigned short* __restrict__ Bbf,
                                               unsigned short* __restrict__ urawb,
                                               unsigned short* __restrict__ zb) {
    __shared__ unsigned short Al[128 * 72];
    __shared__ unsigned short Bl[128 * 72];
    int t = threadIdx.x;
    int mtile = blockIdx.x >> 1, ntile = blockIdx.x & 1;
    int pos0 = mtile * 128, n0g = ntile * 128;
    int lane = t & 63, wv = t >> 6;
    int m0 = (wv & 1) * 64, n0w = (wv >> 1) * 64;
    int lanem = lane & 15, laneq = lane >> 4;
    f32x4 acc[4][4];
    #pragma unroll
    for (int i = 0; i < 4; ++i)
        #pragma unroll
        for (int j = 0; j < 4; ++j) acc[i][j] = (f32x4){0.f, 0.f, 0.f, 0.f};
    for (int kc = 0; kc < 2; ++kc) {
        #pragma unroll
        for (int q = 0; q < 4; ++q) {
            int c = t + q * 256;
            int row = c >> 3, col = c & 7;
            *(int4*)&Al[row * 72 + col * 8] = *(const int4*)&Abf[(pos0 + row) * 128 + kc * 64 + col * 8];
            *(int4*)&Bl[row * 72 + col * 8] = *(const int4*)&Bbf[(n0g + row) * 128 + kc * 64 + col * 8];
        }
        __syncthreads();
        #pragma unroll
        for (int ks = 0; ks < 2; ++ks) {
            short8 af[4], bfr[4];
            #pragma unroll
            for (int mi = 0; mi < 4; ++mi)
                af[mi] = *(const short8*)&Al[(m0 + mi * 16 + lanem) * 72 + ks * 32 + laneq * 8];
            #pragma unroll
            for (int ni = 0; ni < 4; ++ni)
                bfr[ni] = *(const short8*)&Bl[(n0w + ni * 16 + lanem) * 72 + ks * 32 + laneq * 8];
            #pragma unroll
            for (int mi = 0; mi < 4; ++mi)
                #pragma unroll
                for (int ni = 0; ni < 4; ++ni)
                    acc[mi][ni] = __builtin_amdgcn_mfma_f32_16x16x32_bf16(af[mi], bfr[ni], acc[mi][ni], 0, 0, 0);
        }
        __syncthreads();
    }
    unsigned short* dst = ntile ? zb : urawb;
    #pragma unroll
    for (int mi = 0; mi < 4; ++mi)
        #pragma unroll
        for (int ni = 0; ni < 4; ++ni)
            #pragma unroll
            for (int r = 0; r < 4; ++r) {
                int m = pos0 + m0 + mi * 16 + laneq * 4 + r;
                int n = n0w + ni * 16 + lanem;
                dst[m * 128 + n] = f2bf(acc[mi][ni][r]);
            }
}

// ---- K4: conv1d+silu -> usb bf16 ; x_proj MFMA ; delta fp32 ; Bm/Cm ----
__global__ __launch_bounds__(256) void k4_convproj(const unsigned short* __restrict__ urawb,
                                                   const float* __restrict__ cw,
                                                   const float* __restrict__ cb,
                                                   const unsigned short* __restrict__ xpwb,
                                                   const float* __restrict__ dtw,
                                                   const float* __restrict__ dtb,
                                                   unsigned short* __restrict__ usb,
                                                   float* __restrict__ delta,
                                                   float* __restrict__ Bm,
                                                   float* __restrict__ Cm) {
    __shared__ unsigned short uA[64 * 136];
    __shared__ unsigned short xB[32 * 136];
    __shared__ float xdb[64 * 36];
    int t = threadIdx.x;
    int d = t & 127, ph = t >> 7;
    for (int i = t; i < 32 * 128; i += 256) {
        int n = i >> 7, k = i & 127;
        xB[n * 136 + k] = (n < 24) ? xpwb[n * 128 + k] : (unsigned short)0;
    }
    float cw0 = cw[d * 3 + 0], cw1 = cw[d * 3 + 1], cw2 = cw[d * 3 + 2], cbr = cb[d];
    float dtwr[8];
    #pragma unroll
    for (int r = 0; r < 8; ++r) dtwr[r] = dtw[d * 8 + r];
    float dtbr = dtb[d];

    int gpos0 = blockIdx.x * 64;
    int ll0 = (gpos0 & 4095) + ph * 32;
    int base = (gpos0 + ph * 32) * 128 + d;
    float ur0 = (ll0 >= 2) ? bf2f(urawb[base - 256]) : 0.f;
    float ur1 = (ll0 >= 1) ? bf2f(urawb[base - 128]) : 0.f;
    #pragma unroll
    for (int q = 0; q < 32; ++q) {
        float urq = bf2f(urawb[base + q * 128]);
        float v = siluf(ur0 * cw0 + ur1 * cw1 + urq * cw2 + cbr);
        unsigned short vb = f2bf(v);
        usb[base + q * 128] = vb;
        uA[(ph * 32 + q) * 136 + d] = vb;
        ur0 = ur1; ur1 = urq;
    }
    __syncthreads();
    int lane = t & 63, wv = t >> 6;
    int lanem = lane & 15, laneq = lane >> 4;
    f32x4 accx[2];
    accx[0] = (f32x4){0.f, 0.f, 0.f, 0.f};
    accx[1] = (f32x4){0.f, 0.f, 0.f, 0.f};
    #pragma unroll
    for (int ks = 0; ks < 4; ++ks) {
        short8 af = *(const short8*)&uA[(wv * 16 + lanem) * 136 + ks * 32 + laneq * 8];
        #pragma unroll
        for (int nj = 0; nj < 2; ++nj) {
            short8 bfr = *(const short8*)&xB[(nj * 16 + lanem) * 136 + ks * 32 + laneq * 8];
            accx[nj] = __builtin_amdgcn_mfma_f32_16x16x32_bf16(af, bfr, accx[nj], 0, 0, 0);
        }
    }
    #pragma unroll
    for (int nj = 0; nj < 2; ++nj)
        #pragma unroll
        for (int r = 0; r < 4; ++r)
            xdb[(wv * 16 + laneq * 4 + r) * 36 + nj * 16 + lanem] = accx[nj][r];
    __syncthreads();
    #pragma unroll
    for (int q = 0; q < 32; ++q) {
        int pl = ph * 32 + q;
        float dt = dtbr;
        #pragma unroll
        for (int r = 0; r < 8; ++r) dt += xdb[pl * 36 + r] * dtwr[r];
        delta[base + q * 128] = softplusf(dt);
    }
    for (int i = t; i < 1024; i += 256) {
        int p = i >> 4, j = i & 15;
        float v = xdb[p * 36 + 8 + j];
        int gp = gpos0 + p;
        if (j < 8) Bm[gp * 8 + j] = v;
        else       Cm[gp * 8 + (j - 8)] = v;
    }
}

// ---- K5: scan phase 1 (S=16, NC=256). grid B*NC=2048 x 128 thr ----
__global__ __launch_bounds__(128) void k5_scan1(const float* __restrict__ delta,
                                                const unsigned short* __restrict__ usb,
                                                const float* __restrict__ Bm,
                                                const float* __restrict__ A_log,
                                                float* __restrict__ cA,
                                                float* __restrict__ cB) {
    int d = threadIdx.x;
    int bc = blockIdx.x;
    int b = bc >> 8, c = bc & 255;
    float Ar[8]; bool fast = true;
    #pragma unroll
    for (int n = 0; n < 8; ++n) {
        Ar[n] = -__expf(A_log[d * 8 + n]);
        fast = fast && (fabsf(Ar[n] + (float)(n + 1)) < 2e-3f);
    }
    float h[8], ap[8];
    #pragma unroll
    for (int n = 0; n < 8; ++n) { h[n] = 0.f; ap[n] = 1.f; }
    int base  = (b * L_ + c * S_) * 128 + d;
    int bbase = (b * L_ + c * S_) * 8;
    #pragma unroll
    for (int s = 0; s < S_; ++s) {
        float dl = delta[base + s * 128];
        float uv = bf2f(usb[base + s * 128]);
        float du = dl * uv;
        float4 bm0 = *(const float4*)&Bm[bbase + s * 8];
        float4 bm1 = *(const float4*)&Bm[bbase + s * 8 + 4];
        float a[8];
        scan_as(dl, Ar, fast, a);
        ap[0] *= a[0]; h[0] = a[0] * h[0] + du * bm0.x;
        ap[1] *= a[1]; h[1] = a[1] * h[1] + du * bm0.y;
        ap[2] *= a[2]; h[2] = a[2] * h[2] + du * bm0.z;
        ap[3] *= a[3]; h[3] = a[3] * h[3] + du * bm0.w;
        ap[4] *= a[4]; h[4] = a[4] * h[4] + du * bm1.x;
        ap[5] *= a[5]; h[5] = a[5] * h[5] + du * bm1.y;
        ap[6] *= a[6]; h[6] = a[6] * h[6] + du * bm1.z;
        ap[7] *= a[7]; h[7] = a[7] * h[7] + du * bm1.w;
    }
    int obase = ((b * NC_ + c) * 128 + d) * 8;
    *(float4*)&cA[obase]     = make_float4(ap[0], ap[1], ap[2], ap[3]);
    *(float4*)&cA[obase + 4] = make_float4(ap[4], ap[5], ap[6], ap[7]);
    *(float4*)&cB[obase]     = make_float4(h[0], h[1], h[2], h[3]);
    *(float4*)&cB[obase + 4] = make_float4(h[4], h[5], h[6], h[7]);
}

// ---- K6: scan phase 2 (inter-chunk, 256 chunks). 64 blocks x 128 thr ----
__global__ __launch_bounds__(128) void k6_scan2(const float* __restrict__ cA,
                                                const float* __restrict__ cB,
                                                float* __restrict__ carry) {
    int b = blockIdx.x >> 3;
    int slice = blockIdx.x & 7;
    int dn = slice * 128 + threadIdx.x;
    float h = 0.f;
    #pragma unroll 4
    for (int c = 0; c < NC_; ++c) {
        int idx = (b * NC_ + c) * 1024 + dn;
        float a  = cA[idx];
        float bv = cB[idx];
        carry[idx] = h;
        h = a * h + bv;
    }
}

// ---- K7: scan phase 3 (S=16), emit y bf16. grid 2048 x 128 ----
__global__ __launch_bounds__(128) void k7_scan3(const float* __restrict__ delta,
                                                const unsigned short* __restrict__ usb,
                                                const float* __restrict__ Bm,
                                                const float* __restrict__ Cm,
                                                const unsigned short* __restrict__ zb,
                                                const float* __restrict__ A_log,
                                                const float* __restrict__ Dp,
                                                const float* __restrict__ carry,
                                                unsigned short* __restrict__ ybf) {
    int d = threadIdx.x;
    int bc = blockIdx.x;
    int b = bc >> 8, c = bc & 255;
    float Ar[8]; bool fast = true;
    #pragma unroll
    for (int n = 0; n < 8; ++n) {
        Ar[n] = -__expf(A_log[d * 8 + n]);
        fast = fast && (fabsf(Ar[n] + (float)(n + 1)) < 2e-3f);
    }
    float Dpr = Dp[d];
    int cbase = ((b * NC_ + c) * 128 + d) * 8;
    float4 h0 = *(const float4*)&carry[cbase];
    float4 h1 = *(const float4*)&carry[cbase + 4];
    float h[8] = {h0.x, h0.y, h0.z, h0.w, h1.x, h1.y, h1.z, h1.w};
    int base  = (b * L_ + c * S_) * 128 + d;
    int bbase = (b * L_ + c * S_) * 8;
    #pragma unroll
    for (int s = 0; s < S_; ++s) {
        float dl = delta[base + s * 128];
        float uv = bf2f(usb[base + s * 128]);
        float zv = bf2f(zb[base + s * 128]);
        float du = dl * uv;
        float4 bm0 = *(const float4*)&Bm[bbase + s * 8];
        float4 bm1 = *(const float4*)&Bm[bbase + s * 8 + 4];
        float4 cm0 = *(const float4*)&Cm[bbase + s * 8];
        float4 cm1 = *(const float4*)&Cm[bbase + s * 8 + 4];
        float a[8];
        scan_as(dl, Ar, fast, a);
        h[0] = a[0] * h[0] + du * bm0.x;
        h[1] = a[1] * h[1] + du * bm0.y;
        h[2] = a[2] * h[2] + du * bm0.z;
        h[3] = a[3] * h[3] + du * bm0.w;
        h[4] = a[4] * h[4] + du * bm1.x;
        h[5] = a[5] * h[5] + du * bm1.y;
        h[6] = a[6] * h[6] + du * bm1.z;
        h[7] = a[7] * h[7] + du * bm1.w;
        float yv = h[0] * cm0.x + h[1] * cm0.y + h[2] * cm0.z + h[3] * cm0.w
                 + h[4] * cm1.x + h[5] * cm1.y + h[6] * cm1.z + h[7] * cm1.w;
        yv = (yv + uv * Dpr) * siluf(zv);
        ybf[base + s * 128] = f2bf(yv);
    }
}

// ---- K8a: out_proj via bf16 MFMA, 64-row tiles -> xzb bf16. grid 512 ----
__global__ __launch_bounds__(256) void k8a_mfma(const unsigned short* __restrict__ Abf,
                                                const unsigned short* __restrict__ Bbf,
                                                unsigned short* __restrict__ xzb) {
    __shared__ unsigned short Al[64 * 72];
    __shared__ unsigned short Bl[128 * 72];
    int t = threadIdx.x;
    int pos0 = blockIdx.x * 64;
    int lane = t & 63, wv = t >> 6;
    int lanem = lane & 15, laneq = lane >> 4;
    f32x4 acc[8];
    #pragma unroll
    for (int i = 0; i < 8; ++i) acc[i] = (f32x4){0.f, 0.f, 0.f, 0.f};
    for (int kc = 0; kc < 2; ++kc) {
        #pragma unroll
        for (int q = 0; q < 2; ++q) {
            int c = t + q * 256;
            int row = c >> 3, col = c & 7;
            *(int4*)&Al[row * 72 + col * 8] = *(const int4*)&Abf[(pos0 + row) * 128 + kc * 64 + col * 8];
        }
        #pragma unroll
        for (int q = 0; q < 4; ++q) {
            int c = t + q * 256;
            int row = c >> 3, col = c & 7;
            *(int4*)&Bl[row * 72 + col * 8] = *(const int4*)&Bbf[row * 128 + kc * 64 + col * 8];
        }
        __syncthreads();
        #pragma unroll
        for (int ks = 0; ks < 2; ++ks) {
            short8 af = *(const short8*)&Al[(wv * 16 + lanem) * 72 + ks * 32 + laneq * 8];
            #pragma unroll
            for (int ni = 0; ni < 8; ++ni) {
                short8 bfr = *(const short8*)&Bl[(ni * 16 + lanem) * 72 + ks * 32 + laneq * 8];
                acc[ni] = __builtin_amdgcn_mfma_f32_16x16x32_bf16(af, bfr, acc[ni], 0, 0, 0);
            }
        }
        __syncthreads();
    }
    #pragma unroll
    for (int ni = 0; ni < 8; ++ni)
        #pragma unroll
        for (int r = 0; r < 4; ++r) {
            int m = pos0 + wv * 16 + laneq * 4 + r;
            int n = ni * 16 + lanem;
            xzb[m * 128 + n] = f2bf(acc[ni][r]);
        }
}

// ---- K8b: LN + *x2s + wout, register-resident, no xfs LDS. 64 pos/block, grid 512 ----
// thread = (pos = t>>2, g = t&3); 4 threads of one pos are adjacent lanes -> shfl LN.
__global__ __launch_bounds__(256) void k8b_epi(const unsigned short* __restrict__ xzb,
                                               const float* __restrict__ gamma,
                                               const float* __restrict__ beta,
                                               const unsigned short* __restrict__ x2sb,
                                               const float* __restrict__ wout,
                                               float* __restrict__ out) {
    __shared__ float woutL[4 * 1160];   // [g*1160 + o*36 + i]; g banks 8 apart -> parallel
    __shared__ float gbL[256];          // gamma | beta
    int t = threadIdx.x;
    int pos0 = blockIdx.x * 64;
    for (int idx = t; idx < 4096; idx += 256) {
        int g = idx >> 10, r = idx & 1023, o = r >> 5, i = r & 31;
        woutL[g * 1160 + o * 36 + i] = wout[idx];
    }
    if (t < 128) gbL[t] = gamma[t];
    else         gbL[t] = beta[t - 128];
    __syncthreads();

    int g = t & 3, pos = t >> 2;
    int gpos = pos0 + pos;
    float v[32];
    #pragma unroll
    for (int i4 = 0; i4 < 8; ++i4) {
        ushort4 xv = *(const ushort4*)&xzb[gpos * 128 + g * 32 + i4 * 4];
        v[i4*4+0] = bf2f(xv.x); v[i4*4+1] = bf2f(xv.y);
        v[i4*4+2] = bf2f(xv.z); v[i4*4+3] = bf2f(xv.w);
    }
    float s = 0.f, s2 = 0.f;
    #pragma unroll
    for (int i = 0; i < 32; ++i) { s += v[i]; s2 += v[i] * v[i]; }
    s  += __shfl_xor(s, 1, 64);  s  += __shfl_xor(s, 2, 64);
    s2 += __shfl_xor(s2, 1, 64); s2 += __shfl_xor(s2, 2, 64);
    float m = s * (1.f / 128.f);
    float var = s2 * (1.f / 128.f) - m * m;
    float rstd = rsqrtf(var + 1e-5f);
    #pragma unroll
    for (int i4 = 0; i4 < 8; ++i4) {
        ushort4 xv = *(const ushort4*)&x2sb[gpos * 128 + g * 32 + i4 * 4];
        unsigned short xa[4] = {xv.x, xv.y, xv.z, xv.w};
        #pragma unroll
        for (int k = 0; k < 4; ++k) {
            int e = g * 32 + i4 * 4 + k;
            float vv = (v[i4 * 4 + k] - m) * rstd * gbL[e] + gbL[128 + e];
            v[i4 * 4 + k] = vv * bf2f(xa[k]);
        }
    }
    const float* wg = &woutL[g * 1160];
    int obase = gpos * 128 + g * 32;
    #pragma unroll
    for (int ob = 0; ob < 8; ++ob) {
        float o4[4];
        #pragma unroll
        for (int oo = 0; oo < 4; ++oo) {
            int o = ob * 4 + oo;
            float acc = 0.f;
            #pragma unroll
            for (int i4 = 0; i4 < 8; ++i4) {
                float4 wv4 = *(const float4*)&wg[o * 36 + i4 * 4];
                acc += v[i4*4] * wv4.x + v[i4*4+1] * wv4.y
                     + v[i4*4+2] * wv4.z + v[i4*4+3] * wv4.w;
            }
            o4[oo] = acc;
        }
        *(float4*)&out[obase + ob * 4] = make_float4(o4[0], o4[1], o4[2], o4[3]);
    }
}

extern "C" void kernel_launch(void* const* d_in, const int* in_sizes, int n_in,
                              void* d_out, int out_size, void* d_ws, size_t ws_size,
                              hipStream_t stream) {
    (void)in_sizes; (void)n_in; (void)out_size; (void)ws_size;
    const float* x         = (const float*)d_in[0];
    const float* w1        = (const float*)d_in[1];
    const float* dw        = (const float*)d_in[2];
    const float* in_proj_w = (const float*)d_in[3];
    const float* conv1d_w  = (const float*)d_in[4];
    const float* conv1d_b  = (const float*)d_in[5];
    const float* x_proj_w  = (const float*)d_in[6];
    const float* dt_proj_w = (const float*)d_in[7];
    const float* dt_proj_b = (const float*)d_in[8];
    const float* A_log     = (const float*)d_in[9];
    const float* D_param   = (const float*)d_in[10];
    const float* out_proj_w= (const float*)d_in[11];
    const float* gamma     = (const float*)d_in[12];
    const float* beta      = (const float*)d_in[13];
    const float* w2        = (const float*)d_in[14];
    const float* wout      = (const float*)d_in[15];
    float* out = (float*)d_out;

    float* ws = (float*)d_ws;
    unsigned short* x2sb  = (unsigned short*)(ws);
    unsigned short* t1b   = (unsigned short*)(ws + 2  * (size_t)MFL_);
    unsigned short* x1cb  = (unsigned short*)(ws + 4  * (size_t)MFL_);
    unsigned short* urawb = (unsigned short*)(ws + 6  * (size_t)MFL_);
    unsigned short* zb    = (unsigned short*)(ws + 8  * (size_t)MFL_);
    unsigned short* ybf   = (unsigned short*)(ws + 10 * (size_t)MFL_);
    unsigned short* xzb   = (unsigned short*)(ws + 12 * (size_t)MFL_);
    unsigned short* usb   = (unsigned short*)(ws + 14 * (size_t)MFL_);
    float* delta = ws + 16 * (size_t)MFL_;            // 4M fl
    float* Bm    = ws + 20 * (size_t)MFL_;            // 262144
    float* Cm    = Bm + (size_t)NPOS_ * 8;            // 262144
    float* cA    = Cm + (size_t)NPOS_ * 8;            // 2M fl
    float* cB    = cA + 2 * (size_t)MFL_;             // 2M fl
    float* carry = cB + 2 * (size_t)MFL_;             // 2M fl
    unsigned short* inWb = (unsigned short*)(carry + 2 * (size_t)MFL_);
    unsigned short* OWb  = inWb + 32768;
    unsigned short* xpwb = OWb + 16384;

    k0_cvt<<<64, 256, 0, stream>>>(in_proj_w, out_proj_w, x_proj_w, inWb, OWb, xpwb);
    k1_g1x1<<<512, 256, 0, stream>>>(x, w1, w2, t1b, x2sb);
    k2_dwconv<<<512, 128, 0, stream>>>(t1b, dw, x1cb);
    k3_mfma<<<512, 256, 0, stream>>>(x1cb, inWb, urawb, zb);
    k4_convproj<<<512, 256, 0, stream>>>(urawb, conv1d_w, conv1d_b, xpwb,
                                         dt_proj_w, dt_proj_b, usb, delta, Bm, Cm);
    k5_scan1<<<2048, 128, 0, stream>>>(delta, usb, Bm, A_log, cA, cB);
    k6_scan2<<<64, 128, 0, stream>>>(cA, cB, carry);
    k7_scan3<<<2048, 128, 0, stream>>>(delta, usb, Bm, Cm, zb, A_log, D_param, carry, ybf);
    k8a_mfma<<<512, 256, 0, stream>>>(ybf, OWb, xzb);
    k8b_epi<<<512, 256, 0, stream>>>(xzb, gamma, beta, x2sb, wout, out);
}

// Round 11
// 239.575 us; speedup vs baseline: 1.3161x; 1.2733x over previous
//
#include <hip/hip_runtime.h>
#include <math.h>

#define B_    8
#define C_    128
#define D_    128
#define L_    4096
#define NPOS_ 32768
#define NC_   256          // scan chunks per batch
#define S_    16           // chunk length
#define MFL_  1048576

typedef __attribute__((ext_vector_type(8))) short short8;
typedef __attribute__((ext_vector_type(4))) float f32x4;

__device__ __forceinline__ float siluf(float x) { return x / (1.f + __expf(-x)); }
__device__ __forceinline__ float softplusf(float x) {
    if (x > 20.f) return x;
    return __logf(1.f + __expf(x));
}
__device__ __forceinline__ unsigned short f2bf(float f) {
    unsigned int u = __float_as_uint(f);
    u = (u + 0x7FFFu + ((u >> 16) & 1u)) >> 16;
    return (unsigned short)u;
}
__device__ __forceinline__ float bf2f(unsigned short h) {
    return __uint_as_float(((unsigned int)h) << 16);
}
__device__ __forceinline__ void scan_as(float dl, const float* Ar, bool fast, float* a) {
    if (fast) {
        float e1 = __expf(-dl);
        a[0] = e1;
        a[1] = e1 * e1;
        a[2] = a[1] * e1;
        a[3] = a[1] * a[1];
        a[4] = a[3] * e1;
        a[5] = a[3] * a[1];
        a[6] = a[5] * e1;
        a[7] = a[3] * a[3];
    } else {
        #pragma unroll
        for (int n = 0; n < 8; ++n) a[n] = __expf(dl * Ar[n]);
    }
}

// ---- K0: convert in_proj_w, out_proj_w, x_proj_w to bf16 ----
__global__ __launch_bounds__(256) void k0_cvt(const float* __restrict__ inW,
                                              const float* __restrict__ OW,
                                              const float* __restrict__ xpw,
                                              unsigned short* __restrict__ inWb,
                                              unsigned short* __restrict__ OWb,
                                              unsigned short* __restrict__ xpwb) {
    for (int i = blockIdx.x * 256 + threadIdx.x; i < 52224; i += gridDim.x * 256) {
        if (i < 32768)      inWb[i] = f2bf(inW[i]);
        else if (i < 49152) OWb[i - 32768] = f2bf(OW[i - 32768]);
        else                xpwb[i - 49152] = f2bf(xpw[i - 49152]);
    }
}

// ---- K1: grouped 1x1. 32 pos/block, grid 1024 ----
__global__ __launch_bounds__(256) void k1_g1x1(const float* __restrict__ x,
                                               const float* __restrict__ w1,
                                               const float* __restrict__ w2,
                                               unsigned short* __restrict__ t1b,
                                               unsigned short* __restrict__ x2sb) {
    __shared__ float xs[16 * 128];
    int t = threadIdx.x;
    int d = t & 127, ph = t >> 7;
    int g = d >> 5, o = d & 31;
    float w1r[32], w2r[32];
    #pragma unroll
    for (int i = 0; i < 32; ++i) {
        w1r[i] = w1[g * 1024 + o * 32 + i];
        w2r[i] = w2[g * 1024 + o * 32 + i];
    }
    int pos0 = blockIdx.x * 32;
    for (int it = 0; it < 2; ++it) {
        int p0 = pos0 + it * 16;
        #pragma unroll
        for (int q = 0; q < 2; ++q) {
            int fi = t * 2 + q;
            *(float4*)&xs[fi * 4] = *(const float4*)&x[p0 * 128 + fi * 4];
        }
        __syncthreads();
        #pragma unroll
        for (int q = 0; q < 8; ++q) {
            int pl = ph * 8 + q;
            float a1 = 0.f, a2 = 0.f;
            const float* xr = &xs[pl * 128 + g * 32];
            #pragma unroll
            for (int i4 = 0; i4 < 8; ++i4) {
                float4 xv = *(const float4*)&xr[i4 * 4];
                a1 += xv.x * w1r[i4*4] + xv.y * w1r[i4*4+1] + xv.z * w1r[i4*4+2] + xv.w * w1r[i4*4+3];
                a2 += xv.x * w2r[i4*4] + xv.y * w2r[i4*4+1] + xv.z * w2r[i4*4+2] + xv.w * w2r[i4*4+3];
            }
            int pos = p0 + pl;
            t1b[pos * 128 + d]  = f2bf(a1);
            x2sb[pos * 128 + d] = f2bf(siluf(a2));
        }
        __syncthreads();
    }
}

// ---- K2: depthwise 3x3 SAME + silu. bf16 in/out. 8x4 tile, grid 1024 ----
__global__ __launch_bounds__(128) void k2_dwconv(const unsigned short* __restrict__ t1b,
                                                 const float* __restrict__ dw,
                                                 unsigned short* __restrict__ x1cb) {
    int d = threadIdx.x;
    float dwr[9];
    #pragma unroll
    for (int k = 0; k < 9; ++k) dwr[k] = dw[k * 128 + d];
    int bid = blockIdx.x;             // 1024 = b(8) * ht(8) * wt(16)
    int wt = bid & 15, ht = (bid >> 4) & 7, b = bid >> 7;
    int h0 = ht * 8, w0 = wt * 4;
    float rows[10][6];
    #pragma unroll
    for (int r = 0; r < 10; ++r) {
        int hh = h0 - 1 + r;
        bool hv = (hh >= 0) && (hh < 64);
        #pragma unroll
        for (int c = 0; c < 6; ++c) {
            int w = w0 - 1 + c;
            bool wvv = (w >= 0) && (w < 64);
            rows[r][c] = (hv && wvv) ? bf2f(t1b[((b * 64 + hh) * 64 + w) * 128 + d]) : 0.f;
        }
    }
    #pragma unroll
    for (int hi = 0; hi < 8; ++hi) {
        #pragma unroll
        for (int wi = 0; wi < 4; ++wi) {
            float acc = rows[hi][wi]     * dwr[0] + rows[hi][wi+1]   * dwr[1] + rows[hi][wi+2]   * dwr[2]
                      + rows[hi+1][wi]   * dwr[3] + rows[hi+1][wi+1] * dwr[4] + rows[hi+1][wi+2] * dwr[5]
                      + rows[hi+2][wi]   * dwr[6] + rows[hi+2][wi+1] * dwr[7] + rows[hi+2][wi+2] * dwr[8];
            x1cb[((b * 64 + h0 + hi) * 64 + w0 + wi) * 128 + d] = f2bf(siluf(acc));
        }
    }
}

// ---- K3: in_proj via bf16 MFMA, 64-row m-tiles, both halves. grid 1024 ----
__global__ __launch_bounds__(256) void k3_mfma(const unsigned short* __restrict__ Abf,
                                               const unsigned short* __restrict__ Bbf,
                                               unsigned short* __restrict__ urawb,
                                               unsigned short* __restrict__ zb) {
    __shared__ unsigned short Al[64 * 72];
    __shared__ unsigned short Bl[128 * 72];
    int t = threadIdx.x;
    int pos0 = (blockIdx.x >> 1) * 64;
    int half = blockIdx.x & 1;
    const unsigned short* Bh = Bbf + (size_t)half * 128 * 128;
    unsigned short* dst = half ? zb : urawb;
    int lane = t & 63, wv = t >> 6;
    int lanem = lane & 15, laneq = lane >> 4;
    f32x4 acc[8];
    #pragma unroll
    for (int i = 0; i < 8; ++i) acc[i] = (f32x4){0.f, 0.f, 0.f, 0.f};
    for (int kc = 0; kc < 2; ++kc) {
        #pragma unroll
        for (int q = 0; q < 2; ++q) {
            int c = t + q * 256;
            int row = c >> 3, col = c & 7;
            *(int4*)&Al[row * 72 + col * 8] = *(const int4*)&Abf[(pos0 + row) * 128 + kc * 64 + col * 8];
        }
        #pragma unroll
        for (int q = 0; q < 4; ++q) {
            int c = t + q * 256;
            int row = c >> 3, col = c & 7;
            *(int4*)&Bl[row * 72 + col * 8] = *(const int4*)&Bh[row * 128 + kc * 64 + col * 8];
        }
        __syncthreads();
        #pragma unroll
        for (int ks = 0; ks < 2; ++ks) {
            short8 af = *(const short8*)&Al[(wv * 16 + lanem) * 72 + ks * 32 + laneq * 8];
            #pragma unroll
            for (int ni = 0; ni < 8; ++ni) {
                short8 bfr = *(const short8*)&Bl[(ni * 16 + lanem) * 72 + ks * 32 + laneq * 8];
                acc[ni] = __builtin_amdgcn_mfma_f32_16x16x32_bf16(af, bfr, acc[ni], 0, 0, 0);
            }
        }
        __syncthreads();
    }
    #pragma unroll
    for (int ni = 0; ni < 8; ++ni)
        #pragma unroll
        for (int r = 0; r < 4; ++r) {
            int m = pos0 + wv * 16 + laneq * 4 + r;
            int n = ni * 16 + lanem;
            dst[m * 128 + n] = f2bf(acc[ni][r]);
        }
}

// ---- K4: conv1d+silu -> usb ; x_proj MFMA ; delta fp32 ; Bm/Cm. 32 pos/block, grid 1024 ----
__global__ __launch_bounds__(256) void k4_convproj(const unsigned short* __restrict__ urawb,
                                                   const float* __restrict__ cw,
                                                   const float* __restrict__ cb,
                                                   const unsigned short* __restrict__ xpwb,
                                                   const float* __restrict__ dtw,
                                                   const float* __restrict__ dtb,
                                                   unsigned short* __restrict__ usb,
                                                   float* __restrict__ delta,
                                                   float* __restrict__ Bm,
                                                   float* __restrict__ Cm) {
    __shared__ unsigned short uA[32 * 136];
    __shared__ unsigned short xB[32 * 136];
    __shared__ float xdb[32 * 36];
    int t = threadIdx.x;
    int d = t & 127, ph = t >> 7;
    for (int i = t; i < 32 * 128; i += 256) {
        int n = i >> 7, k = i & 127;
        xB[n * 136 + k] = (n < 24) ? xpwb[n * 128 + k] : (unsigned short)0;
    }
    float cw0 = cw[d * 3 + 0], cw1 = cw[d * 3 + 1], cw2 = cw[d * 3 + 2], cbr = cb[d];
    float dtwr[8];
    #pragma unroll
    for (int r = 0; r < 8; ++r) dtwr[r] = dtw[d * 8 + r];
    float dtbr = dtb[d];

    int gpos0 = blockIdx.x * 32;
    int ll0 = (gpos0 & 4095) + ph * 16;
    int base = (gpos0 + ph * 16) * 128 + d;
    float ur0 = (ll0 >= 2) ? bf2f(urawb[base - 256]) : 0.f;
    float ur1 = (ll0 >= 1) ? bf2f(urawb[base - 128]) : 0.f;
    #pragma unroll
    for (int q = 0; q < 16; ++q) {
        float urq = bf2f(urawb[base + q * 128]);
        float v = siluf(ur0 * cw0 + ur1 * cw1 + urq * cw2 + cbr);
        unsigned short vb = f2bf(v);
        usb[base + q * 128] = vb;
        uA[(ph * 16 + q) * 136 + d] = vb;
        ur0 = ur1; ur1 = urq;
    }
    __syncthreads();
    // MFMA: 4 waves = (m-tile, n-tile) 2x2; each 16 pos x 16 e
    int lane = t & 63, wv = t >> 6;
    int lanem = lane & 15, laneq = lane >> 4;
    int m0 = (wv & 1) * 16, n0 = (wv >> 1) * 16;
    f32x4 accx = (f32x4){0.f, 0.f, 0.f, 0.f};
    #pragma unroll
    for (int ks = 0; ks < 4; ++ks) {
        short8 af  = *(const short8*)&uA[(m0 + lanem) * 136 + ks * 32 + laneq * 8];
        short8 bfr = *(const short8*)&xB[(n0 + lanem) * 136 + ks * 32 + laneq * 8];
        accx = __builtin_amdgcn_mfma_f32_16x16x32_bf16(af, bfr, accx, 0, 0, 0);
    }
    #pragma unroll
    for (int r = 0; r < 4; ++r)
        xdb[(m0 + laneq * 4 + r) * 36 + n0 + lanem] = accx[r];
    __syncthreads();
    #pragma unroll
    for (int q = 0; q < 16; ++q) {
        int pl = ph * 16 + q;
        float dt = dtbr;
        #pragma unroll
        for (int r = 0; r < 8; ++r) dt += xdb[pl * 36 + r] * dtwr[r];
        delta[base + q * 128] = softplusf(dt);
    }
    for (int i = t; i < 512; i += 256) {
        int p = i >> 4, j = i & 15;
        float v = xdb[p * 36 + 8 + j];
        int gp = gpos0 + p;
        if (j < 8) Bm[gp * 8 + j] = v;
        else       Cm[gp * 8 + (j - 8)] = v;
    }
}

// ---- K5: scan phase 1 (S=16, NC=256). grid 2048 x 128 ----
__global__ __launch_bounds__(128) void k5_scan1(const float* __restrict__ delta,
                                                const unsigned short* __restrict__ usb,
                                                const float* __restrict__ Bm,
                                                const float* __restrict__ A_log,
                                                float* __restrict__ cA,
                                                float* __restrict__ cB) {
    int d = threadIdx.x;
    int bc = blockIdx.x;
    int b = bc >> 8, c = bc & 255;
    float Ar[8]; bool fast = true;
    #pragma unroll
    for (int n = 0; n < 8; ++n) {
        Ar[n] = -__expf(A_log[d * 8 + n]);
        fast = fast && (fabsf(Ar[n] + (float)(n + 1)) < 2e-3f);
    }
    float h[8], ap[8];
    #pragma unroll
    for (int n = 0; n < 8; ++n) { h[n] = 0.f; ap[n] = 1.f; }
    int base  = (b * L_ + c * S_) * 128 + d;
    int bbase = (b * L_ + c * S_) * 8;
    #pragma unroll
    for (int s = 0; s < S_; ++s) {
        float dl = delta[base + s * 128];
        float uv = bf2f(usb[base + s * 128]);
        float du = dl * uv;
        float4 bm0 = *(const float4*)&Bm[bbase + s * 8];
        float4 bm1 = *(const float4*)&Bm[bbase + s * 8 + 4];
        float a[8];
        scan_as(dl, Ar, fast, a);
        ap[0] *= a[0]; h[0] = a[0] * h[0] + du * bm0.x;
        ap[1] *= a[1]; h[1] = a[1] * h[1] + du * bm0.y;
        ap[2] *= a[2]; h[2] = a[2] * h[2] + du * bm0.z;
        ap[3] *= a[3]; h[3] = a[3] * h[3] + du * bm0.w;
        ap[4] *= a[4]; h[4] = a[4] * h[4] + du * bm1.x;
        ap[5] *= a[5]; h[5] = a[5] * h[5] + du * bm1.y;
        ap[6] *= a[6]; h[6] = a[6] * h[6] + du * bm1.z;
        ap[7] *= a[7]; h[7] = a[7] * h[7] + du * bm1.w;
    }
    int obase = ((b * NC_ + c) * 128 + d) * 8;
    *(float4*)&cA[obase]     = make_float4(ap[0], ap[1], ap[2], ap[3]);
    *(float4*)&cA[obase + 4] = make_float4(ap[4], ap[5], ap[6], ap[7]);
    *(float4*)&cB[obase]     = make_float4(h[0], h[1], h[2], h[3]);
    *(float4*)&cB[obase + 4] = make_float4(h[4], h[5], h[6], h[7]);
}

// ---- K6: scan phase 2 (inter-chunk). 64 blocks x 128 thr ----
__global__ __launch_bounds__(128) void k6_scan2(const float* __restrict__ cA,
                                                const float* __restrict__ cB,
                                                float* __restrict__ carry) {
    int b = blockIdx.x >> 3;
    int slice = blockIdx.x & 7;
    int dn = slice * 128 + threadIdx.x;
    float h = 0.f;
    #pragma unroll 4
    for (int c = 0; c < NC_; ++c) {
        int idx = (b * NC_ + c) * 1024 + dn;
        float a  = cA[idx];
        float bv = cB[idx];
        carry[idx] = h;
        h = a * h + bv;
    }
}

// ---- K7: scan phase 3 (S=16), emit y bf16. grid 2048 x 128 ----
__global__ __launch_bounds__(128) void k7_scan3(const float* __restrict__ delta,
                                                const unsigned short* __restrict__ usb,
                                                const float* __restrict__ Bm,
                                                const float* __restrict__ Cm,
                                                const unsigned short* __restrict__ zb,
                                                const float* __restrict__ A_log,
                                                const float* __restrict__ Dp,
                                                const float* __restrict__ carry,
                                                unsigned short* __restrict__ ybf) {
    int d = threadIdx.x;
    int bc = blockIdx.x;
    int b = bc >> 8, c = bc & 255;
    float Ar[8]; bool fast = true;
    #pragma unroll
    for (int n = 0; n < 8; ++n) {
        Ar[n] = -__expf(A_log[d * 8 + n]);
        fast = fast && (fabsf(Ar[n] + (float)(n + 1)) < 2e-3f);
    }
    float Dpr = Dp[d];
    int cbase = ((b * NC_ + c) * 128 + d) * 8;
    float4 h0 = *(const float4*)&carry[cbase];
    float4 h1 = *(const float4*)&carry[cbase + 4];
    float h[8] = {h0.x, h0.y, h0.z, h0.w, h1.x, h1.y, h1.z, h1.w};
    int base  = (b * L_ + c * S_) * 128 + d;
    int bbase = (b * L_ + c * S_) * 8;
    #pragma unroll
    for (int s = 0; s < S_; ++s) {
        float dl = delta[base + s * 128];
        float uv = bf2f(usb[base + s * 128]);
        float zv = bf2f(zb[base + s * 128]);
        float du = dl * uv;
        float4 bm0 = *(const float4*)&Bm[bbase + s * 8];
        float4 bm1 = *(const float4*)&Bm[bbase + s * 8 + 4];
        float4 cm0 = *(const float4*)&Cm[bbase + s * 8];
        float4 cm1 = *(const float4*)&Cm[bbase + s * 8 + 4];
        float a[8];
        scan_as(dl, Ar, fast, a);
        h[0] = a[0] * h[0] + du * bm0.x;
        h[1] = a[1] * h[1] + du * bm0.y;
        h[2] = a[2] * h[2] + du * bm0.z;
        h[3] = a[3] * h[3] + du * bm0.w;
        h[4] = a[4] * h[4] + du * bm1.x;
        h[5] = a[5] * h[5] + du * bm1.y;
        h[6] = a[6] * h[6] + du * bm1.z;
        h[7] = a[7] * h[7] + du * bm1.w;
        float yv = h[0] * cm0.x + h[1] * cm0.y + h[2] * cm0.z + h[3] * cm0.w
                 + h[4] * cm1.x + h[5] * cm1.y + h[6] * cm1.z + h[7] * cm1.w;
        yv = (yv + uv * Dpr) * siluf(zv);
        ybf[base + s * 128] = f2bf(yv);
    }
}

// ---- K8a: out_proj via bf16 MFMA, 64-row tiles -> xzb bf16. grid 512 ----
__global__ __launch_bounds__(256) void k8a_mfma(const unsigned short* __restrict__ Abf,
                                                const unsigned short* __restrict__ Bbf,
                                                unsigned short* __restrict__ xzb) {
    __shared__ unsigned short Al[64 * 72];
    __shared__ unsigned short Bl[128 * 72];
    int t = threadIdx.x;
    int pos0 = blockIdx.x * 64;
    int lane = t & 63, wv = t >> 6;
    int lanem = lane & 15, laneq = lane >> 4;
    f32x4 acc[8];
    #pragma unroll
    for (int i = 0; i < 8; ++i) acc[i] = (f32x4){0.f, 0.f, 0.f, 0.f};
    for (int kc = 0; kc < 2; ++kc) {
        #pragma unroll
        for (int q = 0; q < 2; ++q) {
            int c = t + q * 256;
            int row = c >> 3, col = c & 7;
            *(int4*)&Al[row * 72 + col * 8] = *(const int4*)&Abf[(pos0 + row) * 128 + kc * 64 + col * 8];
        }
        #pragma unroll
        for (int q = 0; q < 4; ++q) {
            int c = t + q * 256;
            int row = c >> 3, col = c & 7;
            *(int4*)&Bl[row * 72 + col * 8] = *(const int4*)&Bbf[row * 128 + kc * 64 + col * 8];
        }
        __syncthreads();
        #pragma unroll
        for (int ks = 0; ks < 2; ++ks) {
            short8 af = *(const short8*)&Al[(wv * 16 + lanem) * 72 + ks * 32 + laneq * 8];
            #pragma unroll
            for (int ni = 0; ni < 8; ++ni) {
                short8 bfr = *(const short8*)&Bl[(ni * 16 + lanem) * 72 + ks * 32 + laneq * 8];
                acc[ni] = __builtin_amdgcn_mfma_f32_16x16x32_bf16(af, bfr, acc[ni], 0, 0, 0);
            }
        }
        __syncthreads();
    }
    #pragma unroll
    for (int ni = 0; ni < 8; ++ni)
        #pragma unroll
        for (int r = 0; r < 4; ++r) {
            int m = pos0 + wv * 16 + laneq * 4 + r;
            int n = ni * 16 + lanem;
            xzb[m * 128 + n] = f2bf(acc[ni][r]);
        }
}

// ---- K8b: LN + *x2s + wout, register-resident. 64 pos/block, grid 512 ----
__global__ __launch_bounds__(256) void k8b_epi(const unsigned short* __restrict__ xzb,
                                               const float* __restrict__ gamma,
                                               const float* __restrict__ beta,
                                               const unsigned short* __restrict__ x2sb,
                                               const float* __restrict__ wout,
                                               float* __restrict__ out) {
    __shared__ float woutL[4 * 1160];
    __shared__ float gbL[256];
    int t = threadIdx.x;
    int pos0 = blockIdx.x * 64;
    for (int idx = t; idx < 4096; idx += 256) {
        int g = idx >> 10, r = idx & 1023, o = r >> 5, i = r & 31;
        woutL[g * 1160 + o * 36 + i] = wout[idx];
    }
    if (t < 128) gbL[t] = gamma[t];
    else         gbL[t] = beta[t - 128];
    __syncthreads();

    int g = t & 3, pos = t >> 2;
    int gpos = pos0 + pos;
    float v[32];
    #pragma unroll
    for (int i4 = 0; i4 < 8; ++i4) {
        ushort4 xv = *(const ushort4*)&xzb[gpos * 128 + g * 32 + i4 * 4];
        v[i4*4+0] = bf2f(xv.x); v[i4*4+1] = bf2f(xv.y);
        v[i4*4+2] = bf2f(xv.z); v[i4*4+3] = bf2f(xv.w);
    }
    float s = 0.f, s2 = 0.f;
    #pragma unroll
    for (int i = 0; i < 32; ++i) { s += v[i]; s2 += v[i] * v[i]; }
    s  += __shfl_xor(s, 1, 64);  s  += __shfl_xor(s, 2, 64);
    s2 += __shfl_xor(s2, 1, 64); s2 += __shfl_xor(s2, 2, 64);
    float m = s * (1.f / 128.f);
    float var = s2 * (1.f / 128.f) - m * m;
    float rstd = rsqrtf(var + 1e-5f);
    #pragma unroll
    for (int i4 = 0; i4 < 8; ++i4) {
        ushort4 xv = *(const ushort4*)&x2sb[gpos * 128 + g * 32 + i4 * 4];
        unsigned short xa[4] = {xv.x, xv.y, xv.z, xv.w};
        #pragma unroll
        for (int k = 0; k < 4; ++k) {
            int e = g * 32 + i4 * 4 + k;
            float vv = (v[i4 * 4 + k] - m) * rstd * gbL[e] + gbL[128 + e];
            v[i4 * 4 + k] = vv * bf2f(xa[k]);
        }
    }
    const float* wg = &woutL[g * 1160];
    int obase = gpos * 128 + g * 32;
    #pragma unroll
    for (int ob = 0; ob < 8; ++ob) {
        float o4[4];
        #pragma unroll
        for (int oo = 0; oo < 4; ++oo) {
            int o = ob * 4 + oo;
            float acc = 0.f;
            #pragma unroll
            for (int i4 = 0; i4 < 8; ++i4) {
                float4 wv4 = *(const float4*)&wg[o * 36 + i4 * 4];
                acc += v[i4*4] * wv4.x + v[i4*4+1] * wv4.y
                     + v[i4*4+2] * wv4.z + v[i4*4+3] * wv4.w;
            }
            o4[oo] = acc;
        }
        *(float4*)&out[obase + ob * 4] = make_float4(o4[0], o4[1], o4[2], o4[3]);
    }
}

extern "C" void kernel_launch(void* const* d_in, const int* in_sizes, int n_in,
                              void* d_out, int out_size, void* d_ws, size_t ws_size,
                              hipStream_t stream) {
    (void)in_sizes; (void)n_in; (void)out_size; (void)ws_size;
    const float* x         = (const float*)d_in[0];
    const float* w1        = (const float*)d_in[1];
    const float* dw        = (const float*)d_in[2];
    const float* in_proj_w = (const float*)d_in[3];
    const float* conv1d_w  = (const float*)d_in[4];
    const float* conv1d_b  = (const float*)d_in[5];
    const float* x_proj_w  = (const float*)d_in[6];
    const float* dt_proj_w = (const float*)d_in[7];
    const float* dt_proj_b = (const float*)d_in[8];
    const float* A_log     = (const float*)d_in[9];
    const float* D_param   = (const float*)d_in[10];
    const float* out_proj_w= (const float*)d_in[11];
    const float* gamma     = (const float*)d_in[12];
    const float* beta      = (const float*)d_in[13];
    const float* w2        = (const float*)d_in[14];
    const float* wout      = (const float*)d_in[15];
    float* out = (float*)d_out;

    float* ws = (float*)d_ws;
    unsigned short* x2sb  = (unsigned short*)(ws);
    unsigned short* t1b   = (unsigned short*)(ws + 2  * (size_t)MFL_);
    unsigned short* x1cb  = (unsigned short*)(ws + 4  * (size_t)MFL_);
    unsigned short* urawb = (unsigned short*)(ws + 6  * (size_t)MFL_);
    unsigned short* zb    = (unsigned short*)(ws + 8  * (size_t)MFL_);
    unsigned short* ybf   = (unsigned short*)(ws + 10 * (size_t)MFL_);
    unsigned short* xzb   = (unsigned short*)(ws + 12 * (size_t)MFL_);
    unsigned short* usb   = (unsigned short*)(ws + 14 * (size_t)MFL_);
    float* delta = ws + 16 * (size_t)MFL_;            // 4M fl
    float* Bm    = ws + 20 * (size_t)MFL_;            // 262144
    float* Cm    = Bm + (size_t)NPOS_ * 8;            // 262144
    float* cA    = Cm + (size_t)NPOS_ * 8;            // 2M fl
    float* cB    = cA + 2 * (size_t)MFL_;             // 2M fl
    float* carry = cB + 2 * (size_t)MFL_;             // 2M fl
    unsigned short* inWb = (unsigned short*)(carry + 2 * (size_t)MFL_);
    unsigned short* OWb  = inWb + 32768;
    unsigned short* xpwb = OWb + 16384;

    k0_cvt<<<64, 256, 0, stream>>>(in_proj_w, out_proj_w, x_proj_w, inWb, OWb, xpwb);
    k1_g1x1<<<1024, 256, 0, stream>>>(x, w1, w2, t1b, x2sb);
    k2_dwconv<<<1024, 128, 0, stream>>>(t1b, dw, x1cb);
    k3_mfma<<<1024, 256, 0, stream>>>(x1cb, inWb, urawb, zb);
    k4_convproj<<<1024, 256, 0, stream>>>(urawb, conv1d_w, conv1d_b, xpwb,
                                          dt_proj_w, dt_proj_b, usb, delta, Bm, Cm);
    k5_scan1<<<2048, 128, 0, stream>>>(delta, usb, Bm, A_log, cA, cB);
    k6_scan2<<<64, 128, 0, stream>>>(cA, cB, carry);
    k7_scan3<<<2048, 128, 0, stream>>>(delta, usb, Bm, Cm, zb, A_log, D_param, carry, ybf);
    k8a_mfma<<<512, 256, 0, stream>>>(ybf, OWb, xzb);
    k8b_epi<<<512, 256, 0, stream>>>(xzb, gamma, beta, x2sb, wout, out);
}

// Round 12
// 237.521 us; speedup vs baseline: 1.3275x; 1.0086x over previous
//
#include <hip/hip_runtime.h>
#include <math.h>

#define B_    8
#define C_    128
#define D_    128
#define L_    4096
#define NPOS_ 32768
#define NC_   256          // scan chunks per batch
#define S_    16           // chunk length
#define MFL_  1048576

typedef __attribute__((ext_vector_type(8))) short short8;
typedef __attribute__((ext_vector_type(4))) float f32x4;

__device__ __forceinline__ float siluf(float x) { return x / (1.f + __expf(-x)); }
__device__ __forceinline__ float softplusf(float x) {
    if (x > 20.f) return x;
    return __logf(1.f + __expf(x));
}
__device__ __forceinline__ unsigned short f2bf(float f) {
    unsigned int u = __float_as_uint(f);
    u = (u + 0x7FFFu + ((u >> 16) & 1u)) >> 16;
    return (unsigned short)u;
}
__device__ __forceinline__ float bf2f(unsigned short h) {
    return __uint_as_float(((unsigned int)h) << 16);
}
__device__ __forceinline__ void scan_as(float dl, const float* Ar, bool fast, float* a) {
    if (fast) {
        float e1 = __expf(-dl);
        a[0] = e1;
        a[1] = e1 * e1;
        a[2] = a[1] * e1;
        a[3] = a[1] * a[1];
        a[4] = a[3] * e1;
        a[5] = a[3] * a[1];
        a[6] = a[5] * e1;
        a[7] = a[3] * a[3];
    } else {
        #pragma unroll
        for (int n = 0; n < 8; ++n) a[n] = __expf(dl * Ar[n]);
    }
}

// ---- K1: weight cvt (folded k0) + grouped 1x1. 32 pos/block, grid 1024 ----
__global__ __launch_bounds__(256) void k1_g1x1(const float* __restrict__ x,
                                               const float* __restrict__ w1,
                                               const float* __restrict__ w2,
                                               const float* __restrict__ inW,
                                               const float* __restrict__ OW,
                                               const float* __restrict__ xpw,
                                               unsigned short* __restrict__ inWb,
                                               unsigned short* __restrict__ OWb,
                                               unsigned short* __restrict__ xpwb,
                                               unsigned short* __restrict__ t1b,
                                               unsigned short* __restrict__ x2sb) {
    __shared__ float xs[16 * 128];
    int t = threadIdx.x;
    // folded k0: 1024 blocks x 51 = 52224 conversions
    {
        int i = blockIdx.x * 51 + t;
        if (t < 51 && i < 52224) {
            if (i < 32768)      inWb[i] = f2bf(inW[i]);
            else if (i < 49152) OWb[i - 32768] = f2bf(OW[i - 32768]);
            else                xpwb[i - 49152] = f2bf(xpw[i - 49152]);
        }
    }
    int d = t & 127, ph = t >> 7;
    int g = d >> 5, o = d & 31;
    float w1r[32], w2r[32];
    #pragma unroll
    for (int i = 0; i < 32; ++i) {
        w1r[i] = w1[g * 1024 + o * 32 + i];
        w2r[i] = w2[g * 1024 + o * 32 + i];
    }
    int pos0 = blockIdx.x * 32;
    for (int it = 0; it < 2; ++it) {
        int p0 = pos0 + it * 16;
        #pragma unroll
        for (int q = 0; q < 2; ++q) {
            int fi = t * 2 + q;
            *(float4*)&xs[fi * 4] = *(const float4*)&x[p0 * 128 + fi * 4];
        }
        __syncthreads();
        #pragma unroll
        for (int q = 0; q < 8; ++q) {
            int pl = ph * 8 + q;
            float a1 = 0.f, a2 = 0.f;
            const float* xr = &xs[pl * 128 + g * 32];
            #pragma unroll
            for (int i4 = 0; i4 < 8; ++i4) {
                float4 xv = *(const float4*)&xr[i4 * 4];
                a1 += xv.x * w1r[i4*4] + xv.y * w1r[i4*4+1] + xv.z * w1r[i4*4+2] + xv.w * w1r[i4*4+3];
                a2 += xv.x * w2r[i4*4] + xv.y * w2r[i4*4+1] + xv.z * w2r[i4*4+2] + xv.w * w2r[i4*4+3];
            }
            int pos = p0 + pl;
            t1b[pos * 128 + d]  = f2bf(a1);
            x2sb[pos * 128 + d] = f2bf(siluf(a2));
        }
        __syncthreads();
    }
}

// ---- K2: depthwise 3x3 SAME + silu. bf16 in/out. 8x4 tile, grid 1024 ----
__global__ __launch_bounds__(128) void k2_dwconv(const unsigned short* __restrict__ t1b,
                                                 const float* __restrict__ dw,
                                                 unsigned short* __restrict__ x1cb) {
    int d = threadIdx.x;
    float dwr[9];
    #pragma unroll
    for (int k = 0; k < 9; ++k) dwr[k] = dw[k * 128 + d];
    int bid = blockIdx.x;             // 1024 = b(8) * ht(8) * wt(16)
    int wt = bid & 15, ht = (bid >> 4) & 7, b = bid >> 7;
    int h0 = ht * 8, w0 = wt * 4;
    float rows[10][6];
    #pragma unroll
    for (int r = 0; r < 10; ++r) {
        int hh = h0 - 1 + r;
        bool hv = (hh >= 0) && (hh < 64);
        #pragma unroll
        for (int c = 0; c < 6; ++c) {
            int w = w0 - 1 + c;
            bool wvv = (w >= 0) && (w < 64);
            rows[r][c] = (hv && wvv) ? bf2f(t1b[((b * 64 + hh) * 64 + w) * 128 + d]) : 0.f;
        }
    }
    #pragma unroll
    for (int hi = 0; hi < 8; ++hi) {
        #pragma unroll
        for (int wi = 0; wi < 4; ++wi) {
            float acc = rows[hi][wi]     * dwr[0] + rows[hi][wi+1]   * dwr[1] + rows[hi][wi+2]   * dwr[2]
                      + rows[hi+1][wi]   * dwr[3] + rows[hi+1][wi+1] * dwr[4] + rows[hi+1][wi+2] * dwr[5]
                      + rows[hi+2][wi]   * dwr[6] + rows[hi+2][wi+1] * dwr[7] + rows[hi+2][wi+2] * dwr[8];
            x1cb[((b * 64 + h0 + hi) * 64 + w0 + wi) * 128 + d] = f2bf(siluf(acc));
        }
    }
}

// ---- K3: in_proj via bf16 MFMA, 64-row m-tiles, both halves. grid 1024 ----
__global__ __launch_bounds__(256) void k3_mfma(const unsigned short* __restrict__ Abf,
                                               const unsigned short* __restrict__ Bbf,
                                               unsigned short* __restrict__ urawb,
                                               unsigned short* __restrict__ zb) {
    __shared__ unsigned short Al[64 * 72];
    __shared__ unsigned short Bl[128 * 72];
    int t = threadIdx.x;
    int pos0 = (blockIdx.x >> 1) * 64;
    int half = blockIdx.x & 1;
    const unsigned short* Bh = Bbf + (size_t)half * 128 * 128;
    unsigned short* dst = half ? zb : urawb;
    int lane = t & 63, wv = t >> 6;
    int lanem = lane & 15, laneq = lane >> 4;
    f32x4 acc[8];
    #pragma unroll
    for (int i = 0; i < 8; ++i) acc[i] = (f32x4){0.f, 0.f, 0.f, 0.f};
    for (int kc = 0; kc < 2; ++kc) {
        #pragma unroll
        for (int q = 0; q < 2; ++q) {
            int c = t + q * 256;
            int row = c >> 3, col = c & 7;
            *(int4*)&Al[row * 72 + col * 8] = *(const int4*)&Abf[(pos0 + row) * 128 + kc * 64 + col * 8];
        }
        #pragma unroll
        for (int q = 0; q < 4; ++q) {
            int c = t + q * 256;
            int row = c >> 3, col = c & 7;
            *(int4*)&Bl[row * 72 + col * 8] = *(const int4*)&Bh[row * 128 + kc * 64 + col * 8];
        }
        __syncthreads();
        #pragma unroll
        for (int ks = 0; ks < 2; ++ks) {
            short8 af = *(const short8*)&Al[(wv * 16 + lanem) * 72 + ks * 32 + laneq * 8];
            #pragma unroll
            for (int ni = 0; ni < 8; ++ni) {
                short8 bfr = *(const short8*)&Bl[(ni * 16 + lanem) * 72 + ks * 32 + laneq * 8];
                acc[ni] = __builtin_amdgcn_mfma_f32_16x16x32_bf16(af, bfr, acc[ni], 0, 0, 0);
            }
        }
        __syncthreads();
    }
    #pragma unroll
    for (int ni = 0; ni < 8; ++ni)
        #pragma unroll
        for (int r = 0; r < 4; ++r) {
            int m = pos0 + wv * 16 + laneq * 4 + r;
            int n = ni * 16 + lanem;
            dst[m * 128 + n] = f2bf(acc[ni][r]);
        }
}

// ---- K45: conv1d+silu -> usb ; x_proj MFMA ; delta fp32 ; Bm/Cm ; scan phase 1 ----
// 32 pos/block = one S=16 chunk per (d,ph) thread. grid 1024.
__global__ __launch_bounds__(256) void k45_convproj(const unsigned short* __restrict__ urawb,
                                                    const float* __restrict__ cw,
                                                    const float* __restrict__ cb,
                                                    const unsigned short* __restrict__ xpwb,
                                                    const float* __restrict__ dtw,
                                                    const float* __restrict__ dtb,
                                                    const float* __restrict__ A_log,
                                                    unsigned short* __restrict__ usb,
                                                    float* __restrict__ delta,
                                                    float* __restrict__ Bm,
                                                    float* __restrict__ Cm,
                                                    float* __restrict__ cA,
                                                    float* __restrict__ cB) {
    __shared__ unsigned short uA[32 * 136];
    __shared__ unsigned short xB[32 * 136];
    __shared__ float xdb[32 * 36];
    int t = threadIdx.x;
    int d = t & 127, ph = t >> 7;
    for (int i = t; i < 32 * 128; i += 256) {
        int n = i >> 7, k = i & 127;
        xB[n * 136 + k] = (n < 24) ? xpwb[n * 128 + k] : (unsigned short)0;
    }
    float cw0 = cw[d * 3 + 0], cw1 = cw[d * 3 + 1], cw2 = cw[d * 3 + 2], cbr = cb[d];
    float dtwr[8];
    #pragma unroll
    for (int r = 0; r < 8; ++r) dtwr[r] = dtw[d * 8 + r];
    float dtbr = dtb[d];
    float Ar[8]; bool fast = true;
    #pragma unroll
    for (int n = 0; n < 8; ++n) {
        Ar[n] = -__expf(A_log[d * 8 + n]);
        fast = fast && (fabsf(Ar[n] + (float)(n + 1)) < 2e-3f);
    }

    int gpos0 = blockIdx.x * 32;
    int ll0 = (gpos0 & 4095) + ph * 16;
    int base = (gpos0 + ph * 16) * 128 + d;
    float ur0 = (ll0 >= 2) ? bf2f(urawb[base - 256]) : 0.f;
    float ur1 = (ll0 >= 1) ? bf2f(urawb[base - 128]) : 0.f;
    #pragma unroll
    for (int q = 0; q < 16; ++q) {
        float urq = bf2f(urawb[base + q * 128]);
        float v = siluf(ur0 * cw0 + ur1 * cw1 + urq * cw2 + cbr);
        unsigned short vb = f2bf(v);
        usb[base + q * 128] = vb;
        uA[(ph * 16 + q) * 136 + d] = vb;
        ur0 = ur1; ur1 = urq;
    }
    __syncthreads();
    // x_proj MFMA: 4 waves = (m-tile, n-tile) 2x2; each 16 pos x 16 e
    int lane = t & 63, wv = t >> 6;
    int lanem = lane & 15, laneq = lane >> 4;
    int m0 = (wv & 1) * 16, n0 = (wv >> 1) * 16;
    f32x4 accx = (f32x4){0.f, 0.f, 0.f, 0.f};
    #pragma unroll
    for (int ks = 0; ks < 4; ++ks) {
        short8 af  = *(const short8*)&uA[(m0 + lanem) * 136 + ks * 32 + laneq * 8];
        short8 bfr = *(const short8*)&xB[(n0 + lanem) * 136 + ks * 32 + laneq * 8];
        accx = __builtin_amdgcn_mfma_f32_16x16x32_bf16(af, bfr, accx, 0, 0, 0);
    }
    #pragma unroll
    for (int r = 0; r < 4; ++r)
        xdb[(m0 + laneq * 4 + r) * 36 + n0 + lanem] = accx[r];
    __syncthreads();
    // delta + fused scan phase 1 (this thread's chunk: 16 steps)
    float h[8], ap[8];
    #pragma unroll
    for (int n = 0; n < 8; ++n) { h[n] = 0.f; ap[n] = 1.f; }
    #pragma unroll
    for (int q = 0; q < 16; ++q) {
        int pl = ph * 16 + q;
        float dt = dtbr;
        #pragma unroll
        for (int r = 0; r < 8; ++r) dt += xdb[pl * 36 + r] * dtwr[r];
        float dl = softplusf(dt);
        delta[base + q * 128] = dl;
        float du = dl * bf2f(uA[pl * 136 + d]);
        float a[8];
        scan_as(dl, Ar, fast, a);
        #pragma unroll
        for (int n = 0; n < 8; ++n) {
            ap[n] *= a[n];
            h[n] = a[n] * h[n] + du * xdb[pl * 36 + 8 + n];
        }
    }
    int bH = gpos0 >> 12;
    int c  = ((gpos0 & 4095) >> 4) + ph;
    int obase = ((bH * NC_ + c) * 128 + d) * 8;
    *(float4*)&cA[obase]     = make_float4(ap[0], ap[1], ap[2], ap[3]);
    *(float4*)&cA[obase + 4] = make_float4(ap[4], ap[5], ap[6], ap[7]);
    *(float4*)&cB[obase]     = make_float4(h[0], h[1], h[2], h[3]);
    *(float4*)&cB[obase + 4] = make_float4(h[4], h[5], h[6], h[7]);
    // Bm/Cm for k7
    for (int i = t; i < 512; i += 256) {
        int p = i >> 4, j = i & 15;
        float v = xdb[p * 36 + 8 + j];
        int gp = gpos0 + p;
        if (j < 8) Bm[gp * 8 + j] = v;
        else       Cm[gp * 8 + (j - 8)] = v;
    }
}

// ---- K6: scan phase 2 (inter-chunk). 64 blocks x 128 thr ----
__global__ __launch_bounds__(128) void k6_scan2(const float* __restrict__ cA,
                                                const float* __restrict__ cB,
                                                float* __restrict__ carry) {
    int b = blockIdx.x >> 3;
    int slice = blockIdx.x & 7;
    int dn = slice * 128 + threadIdx.x;
    float h = 0.f;
    #pragma unroll 4
    for (int c = 0; c < NC_; ++c) {
        int idx = (b * NC_ + c) * 1024 + dn;
        float a  = cA[idx];
        float bv = cB[idx];
        carry[idx] = h;
        h = a * h + bv;
    }
}

// ---- K7: scan phase 3 (S=16), emit y bf16. grid 2048 x 128 ----
__global__ __launch_bounds__(128) void k7_scan3(const float* __restrict__ delta,
                                                const unsigned short* __restrict__ usb,
                                                const float* __restrict__ Bm,
                                                const float* __restrict__ Cm,
                                                const unsigned short* __restrict__ zb,
                                                const float* __restrict__ A_log,
                                                const float* __restrict__ Dp,
                                                const float* __restrict__ carry,
                                                unsigned short* __restrict__ ybf) {
    int d = threadIdx.x;
    int bc = blockIdx.x;
    int b = bc >> 8, c = bc & 255;
    float Ar[8]; bool fast = true;
    #pragma unroll
    for (int n = 0; n < 8; ++n) {
        Ar[n] = -__expf(A_log[d * 8 + n]);
        fast = fast && (fabsf(Ar[n] + (float)(n + 1)) < 2e-3f);
    }
    float Dpr = Dp[d];
    int cbase = ((b * NC_ + c) * 128 + d) * 8;
    float4 h0 = *(const float4*)&carry[cbase];
    float4 h1 = *(const float4*)&carry[cbase + 4];
    float h[8] = {h0.x, h0.y, h0.z, h0.w, h1.x, h1.y, h1.z, h1.w};
    int base  = (b * L_ + c * S_) * 128 + d;
    int bbase = (b * L_ + c * S_) * 8;
    #pragma unroll
    for (int s = 0; s < S_; ++s) {
        float dl = delta[base + s * 128];
        float uv = bf2f(usb[base + s * 128]);
        float zv = bf2f(zb[base + s * 128]);
        float du = dl * uv;
        float4 bm0 = *(const float4*)&Bm[bbase + s * 8];
        float4 bm1 = *(const float4*)&Bm[bbase + s * 8 + 4];
        float4 cm0 = *(const float4*)&Cm[bbase + s * 8];
        float4 cm1 = *(const float4*)&Cm[bbase + s * 8 + 4];
        float a[8];
        scan_as(dl, Ar, fast, a);
        h[0] = a[0] * h[0] + du * bm0.x;
        h[1] = a[1] * h[1] + du * bm0.y;
        h[2] = a[2] * h[2] + du * bm0.z;
        h[3] = a[3] * h[3] + du * bm0.w;
        h[4] = a[4] * h[4] + du * bm1.x;
        h[5] = a[5] * h[5] + du * bm1.y;
        h[6] = a[6] * h[6] + du * bm1.z;
        h[7] = a[7] * h[7] + du * bm1.w;
        float yv = h[0] * cm0.x + h[1] * cm0.y + h[2] * cm0.z + h[3] * cm0.w
                 + h[4] * cm1.x + h[5] * cm1.y + h[6] * cm1.z + h[7] * cm1.w;
        yv = (yv + uv * Dpr) * siluf(zv);
        ybf[base + s * 128] = f2bf(yv);
    }
}

// ---- K8a: out_proj via bf16 MFMA, 64-row tiles -> xzb bf16. grid 512 ----
__global__ __launch_bounds__(256) void k8a_mfma(const unsigned short* __restrict__ Abf,
                                                const unsigned short* __restrict__ Bbf,
                                                unsigned short* __restrict__ xzb) {
    __shared__ unsigned short Al[64 * 72];
    __shared__ unsigned short Bl[128 * 72];
    int t = threadIdx.x;
    int pos0 = blockIdx.x * 64;
    int lane = t & 63, wv = t >> 6;
    int lanem = lane & 15, laneq = lane >> 4;
    f32x4 acc[8];
    #pragma unroll
    for (int i = 0; i < 8; ++i) acc[i] = (f32x4){0.f, 0.f, 0.f, 0.f};
    for (int kc = 0; kc < 2; ++kc) {
        #pragma unroll
        for (int q = 0; q < 2; ++q) {
            int c = t + q * 256;
            int row = c >> 3, col = c & 7;
            *(int4*)&Al[row * 72 + col * 8] = *(const int4*)&Abf[(pos0 + row) * 128 + kc * 64 + col * 8];
        }
        #pragma unroll
        for (int q = 0; q < 4; ++q) {
            int c = t + q * 256;
            int row = c >> 3, col = c & 7;
            *(int4*)&Bl[row * 72 + col * 8] = *(const int4*)&Bbf[row * 128 + kc * 64 + col * 8];
        }
        __syncthreads();
        #pragma unroll
        for (int ks = 0; ks < 2; ++ks) {
            short8 af = *(const short8*)&Al[(wv * 16 + lanem) * 72 + ks * 32 + laneq * 8];
            #pragma unroll
            for (int ni = 0; ni < 8; ++ni) {
                short8 bfr = *(const short8*)&Bl[(ni * 16 + lanem) * 72 + ks * 32 + laneq * 8];
                acc[ni] = __builtin_amdgcn_mfma_f32_16x16x32_bf16(af, bfr, acc[ni], 0, 0, 0);
            }
        }
        __syncthreads();
    }
    #pragma unroll
    for (int ni = 0; ni < 8; ++ni)
        #pragma unroll
        for (int r = 0; r < 4; ++r) {
            int m = pos0 + wv * 16 + laneq * 4 + r;
            int n = ni * 16 + lanem;
            xzb[m * 128 + n] = f2bf(acc[ni][r]);
        }
}

// ---- K8b: LN + *x2s + wout, register-resident. 64 pos/block, grid 512 ----
__global__ __launch_bounds__(256) void k8b_epi(const unsigned short* __restrict__ xzb,
                                               const float* __restrict__ gamma,
                                               const float* __restrict__ beta,
                                               const unsigned short* __restrict__ x2sb,
                                               const float* __restrict__ wout,
                                               float* __restrict__ out) {
    __shared__ float woutL[4 * 1160];
    __shared__ float gbL[256];
    int t = threadIdx.x;
    int pos0 = blockIdx.x * 64;
    for (int idx = t; idx < 4096; idx += 256) {
        int g = idx >> 10, r = idx & 1023, o = r >> 5, i = r & 31;
        woutL[g * 1160 + o * 36 + i] = wout[idx];
    }
    if (t < 128) gbL[t] = gamma[t];
    else         gbL[t] = beta[t - 128];
    __syncthreads();

    int g = t & 3, pos = t >> 2;
    int gpos = pos0 + pos;
    float v[32];
    #pragma unroll
    for (int i4 = 0; i4 < 8; ++i4) {
        ushort4 xv = *(const ushort4*)&xzb[gpos * 128 + g * 32 + i4 * 4];
        v[i4*4+0] = bf2f(xv.x); v[i4*4+1] = bf2f(xv.y);
        v[i4*4+2] = bf2f(xv.z); v[i4*4+3] = bf2f(xv.w);
    }
    float s = 0.f, s2 = 0.f;
    #pragma unroll
    for (int i = 0; i < 32; ++i) { s += v[i]; s2 += v[i] * v[i]; }
    s  += __shfl_xor(s, 1, 64);  s  += __shfl_xor(s, 2, 64);
    s2 += __shfl_xor(s2, 1, 64); s2 += __shfl_xor(s2, 2, 64);
    float m = s * (1.f / 128.f);
    float var = s2 * (1.f / 128.f) - m * m;
    float rstd = rsqrtf(var + 1e-5f);
    #pragma unroll
    for (int i4 = 0; i4 < 8; ++i4) {
        ushort4 xv = *(const ushort4*)&x2sb[gpos * 128 + g * 32 + i4 * 4];
        unsigned short xa[4] = {xv.x, xv.y, xv.z, xv.w};
        #pragma unroll
        for (int k = 0; k < 4; ++k) {
            int e = g * 32 + i4 * 4 + k;
            float vv = (v[i4 * 4 + k] - m) * rstd * gbL[e] + gbL[128 + e];
            v[i4 * 4 + k] = vv * bf2f(xa[k]);
        }
    }
    const float* wg = &woutL[g * 1160];
    int obase = gpos * 128 + g * 32;
    #pragma unroll
    for (int ob = 0; ob < 8; ++ob) {
        float o4[4];
        #pragma unroll
        for (int oo = 0; oo < 4; ++oo) {
            int o = ob * 4 + oo;
            float acc = 0.f;
            #pragma unroll
            for (int i4 = 0; i4 < 8; ++i4) {
                float4 wv4 = *(const float4*)&wg[o * 36 + i4 * 4];
                acc += v[i4*4] * wv4.x + v[i4*4+1] * wv4.y
                     + v[i4*4+2] * wv4.z + v[i4*4+3] * wv4.w;
            }
            o4[oo] = acc;
        }
        *(float4*)&out[obase + ob * 4] = make_float4(o4[0], o4[1], o4[2], o4[3]);
    }
}

extern "C" void kernel_launch(void* const* d_in, const int* in_sizes, int n_in,
                              void* d_out, int out_size, void* d_ws, size_t ws_size,
                              hipStream_t stream) {
    (void)in_sizes; (void)n_in; (void)out_size; (void)ws_size;
    const float* x         = (const float*)d_in[0];
    const float* w1        = (const float*)d_in[1];
    const float* dw        = (const float*)d_in[2];
    const float* in_proj_w = (const float*)d_in[3];
    const float* conv1d_w  = (const float*)d_in[4];
    const float* conv1d_b  = (const float*)d_in[5];
    const float* x_proj_w  = (const float*)d_in[6];
    const float* dt_proj_w = (const float*)d_in[7];
    const float* dt_proj_b = (const float*)d_in[8];
    const float* A_log     = (const float*)d_in[9];
    const float* D_param   = (const float*)d_in[10];
    const float* out_proj_w= (const float*)d_in[11];
    const float* gamma     = (const float*)d_in[12];
    const float* beta      = (const float*)d_in[13];
    const float* w2        = (const float*)d_in[14];
    const float* wout      = (const float*)d_in[15];
    float* out = (float*)d_out;

    float* ws = (float*)d_ws;
    unsigned short* x2sb  = (unsigned short*)(ws);
    unsigned short* t1b   = (unsigned short*)(ws + 2  * (size_t)MFL_);
    unsigned short* x1cb  = (unsigned short*)(ws + 4  * (size_t)MFL_);
    unsigned short* urawb = (unsigned short*)(ws + 6  * (size_t)MFL_);
    unsigned short* zb    = (unsigned short*)(ws + 8  * (size_t)MFL_);
    unsigned short* ybf   = (unsigned short*)(ws + 10 * (size_t)MFL_);
    unsigned short* xzb   = (unsigned short*)(ws + 12 * (size_t)MFL_);
    unsigned short* usb   = (unsigned short*)(ws + 14 * (size_t)MFL_);
    float* delta = ws + 16 * (size_t)MFL_;            // 4M fl
    float* Bm    = ws + 20 * (size_t)MFL_;            // 262144
    float* Cm    = Bm + (size_t)NPOS_ * 8;            // 262144
    float* cA    = Cm + (size_t)NPOS_ * 8;            // 2M fl
    float* cB    = cA + 2 * (size_t)MFL_;             // 2M fl
    float* carry = cB + 2 * (size_t)MFL_;             // 2M fl
    unsigned short* inWb = (unsigned short*)(carry + 2 * (size_t)MFL_);
    unsigned short* OWb  = inWb + 32768;
    unsigned short* xpwb = OWb + 16384;

    k1_g1x1<<<1024, 256, 0, stream>>>(x, w1, w2, in_proj_w, out_proj_w, x_proj_w,
                                      inWb, OWb, xpwb, t1b, x2sb);
    k2_dwconv<<<1024, 128, 0, stream>>>(t1b, dw, x1cb);
    k3_mfma<<<1024, 256, 0, stream>>>(x1cb, inWb, urawb, zb);
    k45_convproj<<<1024, 256, 0, stream>>>(urawb, conv1d_w, conv1d_b, xpwb,
                                           dt_proj_w, dt_proj_b, A_log,
                                           usb, delta, Bm, Cm, cA, cB);
    k6_scan2<<<64, 128, 0, stream>>>(cA, cB, carry);
    k7_scan3<<<2048, 128, 0, stream>>>(delta, usb, Bm, Cm, zb, A_log, D_param, carry, ybf);
    k8a_mfma<<<512, 256, 0, stream>>>(ybf, OWb, xzb);
    k8b_epi<<<512, 256, 0, stream>>>(xzb, gamma, beta, x2sb, wout, out);
}

// Round 13
// 220.372 us; speedup vs baseline: 1.4308x; 1.0778x over previous
//
#include <hip/hip_runtime.h>
#include <math.h>

#define B_    8
#define C_    128
#define D_    128
#define L_    4096
#define NPOS_ 32768
#define NC_   256          // scan chunks per batch
#define S_    16           // chunk length
#define MFL_  1048576

typedef __attribute__((ext_vector_type(8))) short short8;
typedef __attribute__((ext_vector_type(4))) float f32x4;

__device__ __forceinline__ float siluf(float x) { return x / (1.f + __expf(-x)); }
__device__ __forceinline__ float softplusf(float x) {
    if (x > 20.f) return x;
    return __logf(1.f + __expf(x));
}
__device__ __forceinline__ unsigned short f2bf(float f) {
    unsigned int u = __float_as_uint(f);
    u = (u + 0x7FFFu + ((u >> 16) & 1u)) >> 16;
    return (unsigned short)u;
}
__device__ __forceinline__ float bf2f(unsigned short h) {
    return __uint_as_float(((unsigned int)h) << 16);
}
__device__ __forceinline__ void scan_as(float dl, const float* Ar, bool fast, float* a) {
    if (fast) {
        float e1 = __expf(-dl);
        a[0] = e1;
        a[1] = e1 * e1;
        a[2] = a[1] * e1;
        a[3] = a[1] * a[1];
        a[4] = a[3] * e1;
        a[5] = a[3] * a[1];
        a[6] = a[5] * e1;
        a[7] = a[3] * a[3];
    } else {
        #pragma unroll
        for (int n = 0; n < 8; ++n) a[n] = __expf(dl * Ar[n]);
    }
}

// ---- K1: weight cvt (folded k0) + grouped 1x1. 32 pos/block, grid 1024 ----
__global__ __launch_bounds__(256) void k1_g1x1(const float* __restrict__ x,
                                               const float* __restrict__ w1,
                                               const float* __restrict__ w2,
                                               const float* __restrict__ inW,
                                               const float* __restrict__ OW,
                                               const float* __restrict__ xpw,
                                               unsigned short* __restrict__ inWb,
                                               unsigned short* __restrict__ OWb,
                                               unsigned short* __restrict__ xpwb,
                                               unsigned short* __restrict__ t1b,
                                               unsigned short* __restrict__ x2sb) {
    __shared__ float xs[16 * 128];
    int t = threadIdx.x;
    {
        int i = blockIdx.x * 51 + t;
        if (t < 51 && i < 52224) {
            if (i < 32768)      inWb[i] = f2bf(inW[i]);
            else if (i < 49152) OWb[i - 32768] = f2bf(OW[i - 32768]);
            else                xpwb[i - 49152] = f2bf(xpw[i - 49152]);
        }
    }
    int d = t & 127, ph = t >> 7;
    int g = d >> 5, o = d & 31;
    float w1r[32], w2r[32];
    #pragma unroll
    for (int i = 0; i < 32; ++i) {
        w1r[i] = w1[g * 1024 + o * 32 + i];
        w2r[i] = w2[g * 1024 + o * 32 + i];
    }
    int pos0 = blockIdx.x * 32;
    for (int it = 0; it < 2; ++it) {
        int p0 = pos0 + it * 16;
        #pragma unroll
        for (int q = 0; q < 2; ++q) {
            int fi = t * 2 + q;
            *(float4*)&xs[fi * 4] = *(const float4*)&x[p0 * 128 + fi * 4];
        }
        __syncthreads();
        #pragma unroll
        for (int q = 0; q < 8; ++q) {
            int pl = ph * 8 + q;
            float a1 = 0.f, a2 = 0.f;
            const float* xr = &xs[pl * 128 + g * 32];
            #pragma unroll
            for (int i4 = 0; i4 < 8; ++i4) {
                float4 xv = *(const float4*)&xr[i4 * 4];
                a1 += xv.x * w1r[i4*4] + xv.y * w1r[i4*4+1] + xv.z * w1r[i4*4+2] + xv.w * w1r[i4*4+3];
                a2 += xv.x * w2r[i4*4] + xv.y * w2r[i4*4+1] + xv.z * w2r[i4*4+2] + xv.w * w2r[i4*4+3];
            }
            int pos = p0 + pl;
            t1b[pos * 128 + d]  = f2bf(a1);
            x2sb[pos * 128 + d] = f2bf(siluf(a2));
        }
        __syncthreads();
    }
}

// ---- K2: depthwise 3x3 SAME + silu. bf16 in/out. 8x4 tile, grid 1024 ----
__global__ __launch_bounds__(128) void k2_dwconv(const unsigned short* __restrict__ t1b,
                                                 const float* __restrict__ dw,
                                                 unsigned short* __restrict__ x1cb) {
    int d = threadIdx.x;
    float dwr[9];
    #pragma unroll
    for (int k = 0; k < 9; ++k) dwr[k] = dw[k * 128 + d];
    int bid = blockIdx.x;             // 1024 = b(8) * ht(8) * wt(16)
    int wt = bid & 15, ht = (bid >> 4) & 7, b = bid >> 7;
    int h0 = ht * 8, w0 = wt * 4;
    float rows[10][6];
    #pragma unroll
    for (int r = 0; r < 10; ++r) {
        int hh = h0 - 1 + r;
        bool hv = (hh >= 0) && (hh < 64);
        #pragma unroll
        for (int c = 0; c < 6; ++c) {
            int w = w0 - 1 + c;
            bool wvv = (w >= 0) && (w < 64);
            rows[r][c] = (hv && wvv) ? bf2f(t1b[((b * 64 + hh) * 64 + w) * 128 + d]) : 0.f;
        }
    }
    #pragma unroll
    for (int hi = 0; hi < 8; ++hi) {
        #pragma unroll
        for (int wi = 0; wi < 4; ++wi) {
            float acc = rows[hi][wi]     * dwr[0] + rows[hi][wi+1]   * dwr[1] + rows[hi][wi+2]   * dwr[2]
                      + rows[hi+1][wi]   * dwr[3] + rows[hi+1][wi+1] * dwr[4] + rows[hi+1][wi+2] * dwr[5]
                      + rows[hi+2][wi]   * dwr[6] + rows[hi+2][wi+1] * dwr[7] + rows[hi+2][wi+2] * dwr[8];
            x1cb[((b * 64 + h0 + hi) * 64 + w0 + wi) * 128 + d] = f2bf(siluf(acc));
        }
    }
}

// ---- K3: in_proj via bf16 MFMA, 64-row m-tiles, both halves. grid 1024 ----
__global__ __launch_bounds__(256) void k3_mfma(const unsigned short* __restrict__ Abf,
                                               const unsigned short* __restrict__ Bbf,
                                               unsigned short* __restrict__ urawb,
                                               unsigned short* __restrict__ zb) {
    __shared__ unsigned short Al[64 * 72];
    __shared__ unsigned short Bl[128 * 72];
    int t = threadIdx.x;
    int pos0 = (blockIdx.x >> 1) * 64;
    int half = blockIdx.x & 1;
    const unsigned short* Bh = Bbf + (size_t)half * 128 * 128;
    unsigned short* dst = half ? zb : urawb;
    int lane = t & 63, wv = t >> 6;
    int lanem = lane & 15, laneq = lane >> 4;
    f32x4 acc[8];
    #pragma unroll
    for (int i = 0; i < 8; ++i) acc[i] = (f32x4){0.f, 0.f, 0.f, 0.f};
    for (int kc = 0; kc < 2; ++kc) {
        #pragma unroll
        for (int q = 0; q < 2; ++q) {
            int c = t + q * 256;
            int row = c >> 3, col = c & 7;
            *(int4*)&Al[row * 72 + col * 8] = *(const int4*)&Abf[(pos0 + row) * 128 + kc * 64 + col * 8];
        }
        #pragma unroll
        for (int q = 0; q < 4; ++q) {
            int c = t + q * 256;
            int row = c >> 3, col = c & 7;
            *(int4*)&Bl[row * 72 + col * 8] = *(const int4*)&Bh[row * 128 + kc * 64 + col * 8];
        }
        __syncthreads();
        #pragma unroll
        for (int ks = 0; ks < 2; ++ks) {
            short8 af = *(const short8*)&Al[(wv * 16 + lanem) * 72 + ks * 32 + laneq * 8];
            #pragma unroll
            for (int ni = 0; ni < 8; ++ni) {
                short8 bfr = *(const short8*)&Bl[(ni * 16 + lanem) * 72 + ks * 32 + laneq * 8];
                acc[ni] = __builtin_amdgcn_mfma_f32_16x16x32_bf16(af, bfr, acc[ni], 0, 0, 0);
            }
        }
        __syncthreads();
    }
    #pragma unroll
    for (int ni = 0; ni < 8; ++ni)
        #pragma unroll
        for (int r = 0; r < 4; ++r) {
            int m = pos0 + wv * 16 + laneq * 4 + r;
            int n = ni * 16 + lanem;
            dst[m * 128 + n] = f2bf(acc[ni][r]);
        }
}

// ---- K45: conv1d+silu -> usb ; x_proj MFMA ; delta bf16 ; Bm/Cm ; scan phase 1 ----
__global__ __launch_bounds__(256) void k45_convproj(const unsigned short* __restrict__ urawb,
                                                    const float* __restrict__ cw,
                                                    const float* __restrict__ cb,
                                                    const unsigned short* __restrict__ xpwb,
                                                    const float* __restrict__ dtw,
                                                    const float* __restrict__ dtb,
                                                    const float* __restrict__ A_log,
                                                    unsigned short* __restrict__ usb,
                                                    unsigned short* __restrict__ deltab,
                                                    float* __restrict__ Bm,
                                                    float* __restrict__ Cm,
                                                    float* __restrict__ cA,
                                                    float* __restrict__ cB) {
    __shared__ unsigned short uA[32 * 136];
    __shared__ unsigned short xB[32 * 136];
    __shared__ float xdb[32 * 36];
    int t = threadIdx.x;
    int d = t & 127, ph = t >> 7;
    for (int i = t; i < 32 * 128; i += 256) {
        int n = i >> 7, k = i & 127;
        xB[n * 136 + k] = (n < 24) ? xpwb[n * 128 + k] : (unsigned short)0;
    }
    float cw0 = cw[d * 3 + 0], cw1 = cw[d * 3 + 1], cw2 = cw[d * 3 + 2], cbr = cb[d];
    float dtwr[8];
    #pragma unroll
    for (int r = 0; r < 8; ++r) dtwr[r] = dtw[d * 8 + r];
    float dtbr = dtb[d];
    float Ar[8]; bool fast = true;
    #pragma unroll
    for (int n = 0; n < 8; ++n) {
        Ar[n] = -__expf(A_log[d * 8 + n]);
        fast = fast && (fabsf(Ar[n] + (float)(n + 1)) < 2e-3f);
    }

    int gpos0 = blockIdx.x * 32;
    int ll0 = (gpos0 & 4095) + ph * 16;
    int base = (gpos0 + ph * 16) * 128 + d;
    float ur0 = (ll0 >= 2) ? bf2f(urawb[base - 256]) : 0.f;
    float ur1 = (ll0 >= 1) ? bf2f(urawb[base - 128]) : 0.f;
    #pragma unroll
    for (int q = 0; q < 16; ++q) {
        float urq = bf2f(urawb[base + q * 128]);
        float v = siluf(ur0 * cw0 + ur1 * cw1 + urq * cw2 + cbr);
        unsigned short vb = f2bf(v);
        usb[base + q * 128] = vb;
        uA[(ph * 16 + q) * 136 + d] = vb;
        ur0 = ur1; ur1 = urq;
    }
    __syncthreads();
    int lane = t & 63, wv = t >> 6;
    int lanem = lane & 15, laneq = lane >> 4;
    int m0 = (wv & 1) * 16, n0 = (wv >> 1) * 16;
    f32x4 accx = (f32x4){0.f, 0.f, 0.f, 0.f};
    #pragma unroll
    for (int ks = 0; ks < 4; ++ks) {
        short8 af  = *(const short8*)&uA[(m0 + lanem) * 136 + ks * 32 + laneq * 8];
        short8 bfr = *(const short8*)&xB[(n0 + lanem) * 136 + ks * 32 + laneq * 8];
        accx = __builtin_amdgcn_mfma_f32_16x16x32_bf16(af, bfr, accx, 0, 0, 0);
    }
    #pragma unroll
    for (int r = 0; r < 4; ++r)
        xdb[(m0 + laneq * 4 + r) * 36 + n0 + lanem] = accx[r];
    __syncthreads();
    // delta (bf16 store; scan uses the SAME bf16-rounded value so k7 replay matches)
    float h[8], ap[8];
    #pragma unroll
    for (int n = 0; n < 8; ++n) { h[n] = 0.f; ap[n] = 1.f; }
    #pragma unroll
    for (int q = 0; q < 16; ++q) {
        int pl = ph * 16 + q;
        float dt = dtbr;
        #pragma unroll
        for (int r = 0; r < 8; ++r) dt += xdb[pl * 36 + r] * dtwr[r];
        unsigned short dlb = f2bf(softplusf(dt));
        deltab[base + q * 128] = dlb;
        float dl = bf2f(dlb);
        float du = dl * bf2f(uA[pl * 136 + d]);
        float a[8];
        scan_as(dl, Ar, fast, a);
        #pragma unroll
        for (int n = 0; n < 8; ++n) {
            ap[n] *= a[n];
            h[n] = a[n] * h[n] + du * xdb[pl * 36 + 8 + n];
        }
    }
    int bH = gpos0 >> 12;
    int c  = ((gpos0 & 4095) >> 4) + ph;
    int obase = ((bH * NC_ + c) * 128 + d) * 8;
    *(float4*)&cA[obase]     = make_float4(ap[0], ap[1], ap[2], ap[3]);
    *(float4*)&cA[obase + 4] = make_float4(ap[4], ap[5], ap[6], ap[7]);
    *(float4*)&cB[obase]     = make_float4(h[0], h[1], h[2], h[3]);
    *(float4*)&cB[obase + 4] = make_float4(h[4], h[5], h[6], h[7]);
    for (int i = t; i < 512; i += 256) {
        int p = i >> 4, j = i & 15;
        float v = xdb[p * 36 + 8 + j];
        int gp = gpos0 + p;
        if (j < 8) Bm[gp * 8 + j] = v;
        else       Cm[gp * 8 + (j - 8)] = v;
    }
}

// ---- K6: scan phase 2 (inter-chunk). 64 blocks x 128 thr, deep unroll ----
__global__ __launch_bounds__(128) void k6_scan2(const float* __restrict__ cA,
                                                const float* __restrict__ cB,
                                                float* __restrict__ carry) {
    int b = blockIdx.x >> 3;
    int slice = blockIdx.x & 7;
    int dn = slice * 128 + threadIdx.x;
    float h = 0.f;
    #pragma unroll 8
    for (int c = 0; c < NC_; ++c) {
        int idx = (b * NC_ + c) * 1024 + dn;
        float a  = cA[idx];
        float bv = cB[idx];
        carry[idx] = h;
        h = a * h + bv;
    }
}

// ---- K7: scan phase 3 (S=16), emit y bf16. grid 2048 x 128 ----
__global__ __launch_bounds__(128) void k7_scan3(const unsigned short* __restrict__ deltab,
                                                const unsigned short* __restrict__ usb,
                                                const float* __restrict__ Bm,
                                                const float* __restrict__ Cm,
                                                const unsigned short* __restrict__ zb,
                                                const float* __restrict__ A_log,
                                                const float* __restrict__ Dp,
                                                const float* __restrict__ carry,
                                                unsigned short* __restrict__ ybf) {
    int d = threadIdx.x;
    int bc = blockIdx.x;
    int b = bc >> 8, c = bc & 255;
    float Ar[8]; bool fast = true;
    #pragma unroll
    for (int n = 0; n < 8; ++n) {
        Ar[n] = -__expf(A_log[d * 8 + n]);
        fast = fast && (fabsf(Ar[n] + (float)(n + 1)) < 2e-3f);
    }
    float Dpr = Dp[d];
    int cbase = ((b * NC_ + c) * 128 + d) * 8;
    float4 h0 = *(const float4*)&carry[cbase];
    float4 h1 = *(const float4*)&carry[cbase + 4];
    float h[8] = {h0.x, h0.y, h0.z, h0.w, h1.x, h1.y, h1.z, h1.w};
    int base  = (b * L_ + c * S_) * 128 + d;
    int bbase = (b * L_ + c * S_) * 8;
    #pragma unroll
    for (int s = 0; s < S_; ++s) {
        float dl = bf2f(deltab[base + s * 128]);
        float uv = bf2f(usb[base + s * 128]);
        float zv = bf2f(zb[base + s * 128]);
        float du = dl * uv;
        float4 bm0 = *(const float4*)&Bm[bbase + s * 8];
        float4 bm1 = *(const float4*)&Bm[bbase + s * 8 + 4];
        float4 cm0 = *(const float4*)&Cm[bbase + s * 8];
        float4 cm1 = *(const float4*)&Cm[bbase + s * 8 + 4];
        float a[8];
        scan_as(dl, Ar, fast, a);
        h[0] = a[0] * h[0] + du * bm0.x;
        h[1] = a[1] * h[1] + du * bm0.y;
        h[2] = a[2] * h[2] + du * bm0.z;
        h[3] = a[3] * h[3] + du * bm0.w;
        h[4] = a[4] * h[4] + du * bm1.x;
        h[5] = a[5] * h[5] + du * bm1.y;
        h[6] = a[6] * h[6] + du * bm1.z;
        h[7] = a[7] * h[7] + du * bm1.w;
        float yv = h[0] * cm0.x + h[1] * cm0.y + h[2] * cm0.z + h[3] * cm0.w
                 + h[4] * cm1.x + h[5] * cm1.y + h[6] * cm1.z + h[7] * cm1.w;
        yv = (yv + uv * Dpr) * siluf(zv);
        ybf[base + s * 128] = f2bf(yv);
    }
}

// ---- K8a: out_proj via bf16 MFMA, 64-row tiles -> xzb bf16. grid 512 ----
__global__ __launch_bounds__(256) void k8a_mfma(const unsigned short* __restrict__ Abf,
                                                const unsigned short* __restrict__ Bbf,
                                                unsigned short* __restrict__ xzb) {
    __shared__ unsigned short Al[64 * 72];
    __shared__ unsigned short Bl[128 * 72];
    int t = threadIdx.x;
    int pos0 = blockIdx.x * 64;
    int lane = t & 63, wv = t >> 6;
    int lanem = lane & 15, laneq = lane >> 4;
    f32x4 acc[8];
    #pragma unroll
    for (int i = 0; i < 8; ++i) acc[i] = (f32x4){0.f, 0.f, 0.f, 0.f};
    for (int kc = 0; kc < 2; ++kc) {
        #pragma unroll
        for (int q = 0; q < 2; ++q) {
            int c = t + q * 256;
            int row = c >> 3, col = c & 7;
            *(int4*)&Al[row * 72 + col * 8] = *(const int4*)&Abf[(pos0 + row) * 128 + kc * 64 + col * 8];
        }
        #pragma unroll
        for (int q = 0; q < 4; ++q) {
            int c = t + q * 256;
            int row = c >> 3, col = c & 7;
            *(int4*)&Bl[row * 72 + col * 8] = *(const int4*)&Bbf[row * 128 + kc * 64 + col * 8];
        }
        __syncthreads();
        #pragma unroll
        for (int ks = 0; ks < 2; ++ks) {
            short8 af = *(const short8*)&Al[(wv * 16 + lanem) * 72 + ks * 32 + laneq * 8];
            #pragma unroll
            for (int ni = 0; ni < 8; ++ni) {
                short8 bfr = *(const short8*)&Bl[(ni * 16 + lanem) * 72 + ks * 32 + laneq * 8];
                acc[ni] = __builtin_amdgcn_mfma_f32_16x16x32_bf16(af, bfr, acc[ni], 0, 0, 0);
            }
        }
        __syncthreads();
    }
    #pragma unroll
    for (int ni = 0; ni < 8; ++ni)
        #pragma unroll
        for (int r = 0; r < 4; ++r) {
            int m = pos0 + wv * 16 + laneq * 4 + r;
            int n = ni * 16 + lanem;
            xzb[m * 128 + n] = f2bf(acc[ni][r]);
        }
}

// ---- K8b: LN + *x2s + wout, register-resident. 64 pos/block, grid 512 ----
__global__ __launch_bounds__(256) void k8b_epi(const unsigned short* __restrict__ xzb,
                                               const float* __restrict__ gamma,
                                               const float* __restrict__ beta,
                                               const unsigned short* __restrict__ x2sb,
                                               const float* __restrict__ wout,
                                               float* __restrict__ out) {
    __shared__ float woutL[4 * 1160];
    __shared__ float gbL[256];
    int t = threadIdx.x;
    int pos0 = blockIdx.x * 64;
    for (int idx = t; idx < 4096; idx += 256) {
        int g = idx >> 10, r = idx & 1023, o = r >> 5, i = r & 31;
        woutL[g * 1160 + o * 36 + i] = wout[idx];
    }
    if (t < 128) gbL[t] = gamma[t];
    else         gbL[t] = beta[t - 128];
    __syncthreads();

    int g = t & 3, pos = t >> 2;
    int gpos = pos0 + pos;
    float v[32];
    #pragma unroll
    for (int i4 = 0; i4 < 8; ++i4) {
        ushort4 xv = *(const ushort4*)&xzb[gpos * 128 + g * 32 + i4 * 4];
        v[i4*4+0] = bf2f(xv.x); v[i4*4+1] = bf2f(xv.y);
        v[i4*4+2] = bf2f(xv.z); v[i4*4+3] = bf2f(xv.w);
    }
    float s = 0.f, s2 = 0.f;
    #pragma unroll
    for (int i = 0; i < 32; ++i) { s += v[i]; s2 += v[i] * v[i]; }
    s  += __shfl_xor(s, 1, 64);  s  += __shfl_xor(s, 2, 64);
    s2 += __shfl_xor(s2, 1, 64); s2 += __shfl_xor(s2, 2, 64);
    float m = s * (1.f / 128.f);
    float var = s2 * (1.f / 128.f) - m * m;
    float rstd = rsqrtf(var + 1e-5f);
    #pragma unroll
    for (int i4 = 0; i4 < 8; ++i4) {
        ushort4 xv = *(const ushort4*)&x2sb[gpos * 128 + g * 32 + i4 * 4];
        unsigned short xa[4] = {xv.x, xv.y, xv.z, xv.w};
        #pragma unroll
        for (int k = 0; k < 4; ++k) {
            int e = g * 32 + i4 * 4 + k;
            float vv = (v[i4 * 4 + k] - m) * rstd * gbL[e] + gbL[128 + e];
            v[i4 * 4 + k] = vv * bf2f(xa[k]);
        }
    }
    const float* wg = &woutL[g * 1160];
    int obase = gpos * 128 + g * 32;
    #pragma unroll
    for (int ob = 0; ob < 8; ++ob) {
        float o4[4];
        #pragma unroll
        for (int oo = 0; oo < 4; ++oo) {
            int o = ob * 4 + oo;
            float acc = 0.f;
            #pragma unroll
            for (int i4 = 0; i4 < 8; ++i4) {
                float4 wv4 = *(const float4*)&wg[o * 36 + i4 * 4];
                acc += v[i4*4] * wv4.x + v[i4*4+1] * wv4.y
                     + v[i4*4+2] * wv4.z + v[i4*4+3] * wv4.w;
            }
            o4[oo] = acc;
        }
        *(float4*)&out[obase + ob * 4] = make_float4(o4[0], o4[1], o4[2], o4[3]);
    }
}

extern "C" void kernel_launch(void* const* d_in, const int* in_sizes, int n_in,
                              void* d_out, int out_size, void* d_ws, size_t ws_size,
                              hipStream_t stream) {
    (void)in_sizes; (void)n_in; (void)out_size; (void)ws_size;
    const float* x         = (const float*)d_in[0];
    const float* w1        = (const float*)d_in[1];
    const float* dw        = (const float*)d_in[2];
    const float* in_proj_w = (const float*)d_in[3];
    const float* conv1d_w  = (const float*)d_in[4];
    const float* conv1d_b  = (const float*)d_in[5];
    const float* x_proj_w  = (const float*)d_in[6];
    const float* dt_proj_w = (const float*)d_in[7];
    const float* dt_proj_b = (const float*)d_in[8];
    const float* A_log     = (const float*)d_in[9];
    const float* D_param   = (const float*)d_in[10];
    const float* out_proj_w= (const float*)d_in[11];
    const float* gamma     = (const float*)d_in[12];
    const float* beta      = (const float*)d_in[13];
    const float* w2        = (const float*)d_in[14];
    const float* wout      = (const float*)d_in[15];
    float* out = (float*)d_out;

    float* ws = (float*)d_ws;
    unsigned short* x2sb   = (unsigned short*)(ws);
    unsigned short* t1b    = (unsigned short*)(ws + 2  * (size_t)MFL_);
    unsigned short* x1cb   = (unsigned short*)(ws + 4  * (size_t)MFL_);
    unsigned short* urawb  = (unsigned short*)(ws + 6  * (size_t)MFL_);
    unsigned short* zb     = (unsigned short*)(ws + 8  * (size_t)MFL_);
    unsigned short* ybf    = (unsigned short*)(ws + 10 * (size_t)MFL_);
    unsigned short* xzb    = (unsigned short*)(ws + 12 * (size_t)MFL_);
    unsigned short* usb    = (unsigned short*)(ws + 14 * (size_t)MFL_);
    unsigned short* deltab = (unsigned short*)(ws + 16 * (size_t)MFL_);  // bf16 now
    float* Bm    = ws + 18 * (size_t)MFL_;            // 262144
    float* Cm    = Bm + (size_t)NPOS_ * 8;            // 262144
    float* cA    = Cm + (size_t)NPOS_ * 8;            // 2M fl
    float* cB    = cA + 2 * (size_t)MFL_;             // 2M fl
    float* carry = cB + 2 * (size_t)MFL_;             // 2M fl
    unsigned short* inWb = (unsigned short*)(carry + 2 * (size_t)MFL_);
    unsigned short* OWb  = inWb + 32768;
    unsigned short* xpwb = OWb + 16384;

    k1_g1x1<<<1024, 256, 0, stream>>>(x, w1, w2, in_proj_w, out_proj_w, x_proj_w,
                                      inWb, OWb, xpwb, t1b, x2sb);
    k2_dwconv<<<1024, 128, 0, stream>>>(t1b, dw, x1cb);
    k3_mfma<<<1024, 256, 0, stream>>>(x1cb, inWb, urawb, zb);
    k45_convproj<<<1024, 256, 0, stream>>>(urawb, conv1d_w, conv1d_b, xpwb,
                                           dt_proj_w, dt_proj_b, A_log,
                                           usb, deltab, Bm, Cm, cA, cB);
    k6_scan2<<<64, 128, 0, stream>>>(cA, cB, carry);
    k7_scan3<<<2048, 128, 0, stream>>>(deltab, usb, Bm, Cm, zb, A_log, D_param, carry, ybf);
    k8a_mfma<<<512, 256, 0, stream>>>(ybf, OWb, xzb);
    k8b_epi<<<512, 256, 0, stream>>>(xzb, gamma, beta, x2sb, wout, out);
}